// Round 1
// baseline (369.676 us; speedup 1.0000x reference)
//
#include <hip/hip_runtime.h>
#include <math.h>

#define BB 32
#define LL 2048
#define EE 512
#define HH 512

typedef __bf16 bf16_t;
typedef bf16_t bf16x8 __attribute__((ext_vector_type(8)));
typedef float f32x4 __attribute__((ext_vector_type(4)));
typedef unsigned short u16x8 __attribute__((ext_vector_type(8)));

__device__ __forceinline__ unsigned short f2bf(float f) {
  unsigned int u = __builtin_bit_cast(unsigned int, f);
  unsigned int r = (u + 0x7FFFu + ((u >> 16) & 1u)) >> 16;  // RNE
  return (unsigned short)r;
}
__device__ __forceinline__ float bf2f(unsigned short s) {
  unsigned int u = ((unsigned int)s) << 16;
  return __builtin_bit_cast(float, u);
}
__device__ __forceinline__ bf16x8 ld_frag(const unsigned short* p) {
  u16x8 raw = *(const u16x8*)p;
  return __builtin_bit_cast(bf16x8, raw);
}
__device__ __forceinline__ float tanh_fast(float x) {
  x = fminf(fmaxf(x, -15.f), 15.f);
  float e2 = __expf(2.f * x);
  return (e2 - 1.f) / (e2 + 1.f);
}

// load the 4 A/B weight fragments (one 64-row x 32-k window) DIRECTLY global->reg
// in MFMA fragment layout. Each frag = 16 rows x 64B contiguous; weights (1MB bf16
// total) are L2-resident, and each element feeds exactly ONE MFMA, so LDS staging
// was a pure write+read round-trip (and the 64KB slab capped us at 1 block/CU).
__device__ __forceinline__ void frag_issue(const unsigned short* __restrict__ g,
                                           int k0, bf16x8 f[4]) {
#pragma unroll
  for (int i = 0; i < 4; i++) f[i] = ld_frag(g + (size_t)i * 16 * 512 + k0);
}

// ---------------- prep: transpose + fp32->bf16 convert of Wh, Wc; init work queue ----------------
__global__ __launch_bounds__(256) void prep_w(
    const float* __restrict__ Wh, const float* __restrict__ Wc,
    unsigned short* __restrict__ WhT, unsigned short* __restrict__ WcT,
    int* __restrict__ q)
{
  if (blockIdx.x == 0 && blockIdx.y == 0 && threadIdx.x == 0) *q = 0;
  const float* src = blockIdx.y ? Wc : Wh;
  unsigned short* dst = blockIdx.y ? WcT : WhT;
  const int tr = (blockIdx.x >> 3) * 64;
  const int tc = (blockIdx.x & 7) * 64;
  const int tid = threadIdx.x;
  __shared__ float tile[64][65];
  for (int i = tid; i < 64 * 16; i += 256) {
    const int r = i >> 4, c4 = (i & 15) << 2;
    const float4 v = *(const float4*)(src + (size_t)(tr + r) * 512 + tc + c4);
    tile[r][c4 + 0] = v.x; tile[r][c4 + 1] = v.y;
    tile[r][c4 + 2] = v.z; tile[r][c4 + 3] = v.w;
  }
  __syncthreads();
  for (int i = tid; i < 64 * 16; i += 256) {
    const int r = i >> 4, c4 = (i & 15) << 2;
    ushort4 pk;
    pk.x = f2bf(tile[c4 + 0][r]); pk.y = f2bf(tile[c4 + 1][r]);
    pk.z = f2bf(tile[c4 + 2][r]); pk.w = f2bf(tile[c4 + 3][r]);
    *(ushort4*)(dst + (size_t)(tc + r) * 512 + tr + c4) = pk;
  }
}

// ---------------- main: persistent blocks pop (b,c) items; k-loop rotated per (item,wave) ----------------
// LDS = encA + hS + bh ~= 68.6 KB -> 2 blocks/CU resident (was 134.7 KB -> 1 block/CU).
// With two independent blocks per CU, the barrier-separated phases overlap across blocks.
__global__ __launch_bounds__(512, 4) void attn_main(
    const float* __restrict__ enc, const int* __restrict__ lens,
    const unsigned short* __restrict__ WhT, const float* __restrict__ bh,
    const unsigned short* __restrict__ WcT,
    float* __restrict__ pm, float* __restrict__ ps, float* __restrict__ po,
    int* __restrict__ q, int C, int Lc)
{
  const int tid  = threadIdx.x;
  const int wave = tid >> 6;       // 0..7
  const int lane = tid & 63;
  const int quad = lane >> 4;
  const int l15  = lane & 15;
  const int wbase = wave * 64;     // wave's 64-wide h-slab (GEMM1) / e-slab (GEMM2)

  __shared__ __align__(16) unsigned short encA[32 * 520];  // 33.3 KB
  __shared__ __align__(16) unsigned short hS[32 * 520];    // 33.3 KB
  __shared__ __align__(16) float bhS[512];
  __shared__ int itemS;

  bhS[tid] = bh[tid];
  const int nitems = 32 * C;

#pragma unroll 1
  for (;;) {
    __syncthreads();                       // protect itemS + LDS from previous item
    if (tid == 0) itemS = atomicAdd(q, 1);
    __syncthreads();
    const int item = itemS;
    if (item >= nitems) break;            // uniform across block
    const int b = item & 31;
    const int c = item >> 5;
    const int n = lens[b];
    const int l0 = c * Lc;
    const int nvalid = min(n - l0, Lc);
    if (nvalid <= 0) continue;

    const int phase = (item + wave) & 15;  // k-window de-phasing across waves/items

    float stM[4], stS[4], stO[4];
#pragma unroll
    for (int et = 0; et < 4; et++) { stM[et] = -1e30f; stS[et] = 0.f; stO[et] = 0.f; }

#pragma unroll 1
    for (int r0 = 0; r0 < nvalid; r0 += 32) {
      // ---- stage enc tile -> bf16 LDS (one copy shared by 8 waves) ----
      const float* encRow = enc + ((size_t)b * LL + l0 + r0) * EE;
      for (int i = tid; i < 32 * 128; i += 512) {
        const int m = i >> 7, e4 = (i & 127) << 2;
        const float4 v = *(const float4*)(encRow + (size_t)m * EE + e4);
        ushort4 pk;
        pk.x = f2bf(v.x); pk.y = f2bf(v.y); pk.z = f2bf(v.z); pk.w = f2bf(v.w);
        *(ushort4*)&encA[m * 520 + e4] = pk;
      }
      __syncthreads();

      // ================= GEMM1: hT[64 x 32] per wave = WhT @ encT =================
      f32x4 acc1[4][2];
#pragma unroll
      for (int t = 0; t < 4; t++)
        for (int mt = 0; mt < 2; mt++) acc1[t][mt] = (f32x4){0.f, 0.f, 0.f, 0.f};
      {
        const unsigned short* baseW = WhT + (size_t)(wbase + l15) * 512 + quad * 8;
        bf16x8 fA[4], fB[4];
        frag_issue(baseW, ((0 + phase) & 15) * 32, fA);
        frag_issue(baseW, ((1 + phase) & 15) * 32, fB);
#pragma unroll 1
        for (int kk = 0; kk < 16; kk += 2) {
          {
            const int k0 = ((kk + phase) & 15) * 32;
            const bf16x8 b0 = ld_frag(&encA[l15 * 520 + k0 + quad * 8]);
            const bf16x8 b1 = ld_frag(&encA[(16 + l15) * 520 + k0 + quad * 8]);
#pragma unroll
            for (int t = 0; t < 4; t++) {
              acc1[t][0] = __builtin_amdgcn_mfma_f32_16x16x32_bf16(fA[t], b0, acc1[t][0], 0, 0, 0);
              acc1[t][1] = __builtin_amdgcn_mfma_f32_16x16x32_bf16(fA[t], b1, acc1[t][1], 0, 0, 0);
            }
            if (kk + 2 < 16) frag_issue(baseW, ((kk + 2 + phase) & 15) * 32, fA);
          }
          {
            const int k0 = ((kk + 1 + phase) & 15) * 32;
            const bf16x8 b0 = ld_frag(&encA[l15 * 520 + k0 + quad * 8]);
            const bf16x8 b1 = ld_frag(&encA[(16 + l15) * 520 + k0 + quad * 8]);
#pragma unroll
            for (int t = 0; t < 4; t++) {
              acc1[t][0] = __builtin_amdgcn_mfma_f32_16x16x32_bf16(fB[t], b0, acc1[t][0], 0, 0, 0);
              acc1[t][1] = __builtin_amdgcn_mfma_f32_16x16x32_bf16(fB[t], b1, acc1[t][1], 0, 0, 0);
            }
            if (kk + 3 < 16) frag_issue(baseW, ((kk + 3 + phase) & 15) * 32, fB);
          }
        }
      }

      // ---- bias + tanh, pack 4 consecutive h -> one 8B LDS write of h[m][h] ----
#pragma unroll
      for (int t = 0; t < 4; t++) {
        const f32x4 bv = *(const f32x4*)&bhS[wbase + t * 16 + quad * 4];
#pragma unroll
        for (int mt = 0; mt < 2; mt++) {
          ushort4 pk;
          pk.x = f2bf(tanh_fast(acc1[t][mt][0] + bv[0]));
          pk.y = f2bf(tanh_fast(acc1[t][mt][1] + bv[1]));
          pk.z = f2bf(tanh_fast(acc1[t][mt][2] + bv[2]));
          pk.w = f2bf(tanh_fast(acc1[t][mt][3] + bv[3]));
          *(ushort4*)&hS[(mt * 16 + l15) * 520 + wbase + t * 16 + quad * 4] = pk;
        }
      }
      __syncthreads();

      // ================= GEMM2: logits[32 x 64] per wave = h @ WcT-slab =================
      f32x4 acc2[2][4];
#pragma unroll
      for (int mt = 0; mt < 2; mt++)
        for (int et = 0; et < 4; et++) acc2[mt][et] = (f32x4){0.f, 0.f, 0.f, 0.f};
      {
        const unsigned short* baseW = WcT + (size_t)(wbase + l15) * 512 + quad * 8;
        bf16x8 fA[4], fB[4];
        frag_issue(baseW, ((0 + phase) & 15) * 32, fA);
        frag_issue(baseW, ((1 + phase) & 15) * 32, fB);
#pragma unroll 1
        for (int kk = 0; kk < 16; kk += 2) {
          {
            const int k0 = ((kk + phase) & 15) * 32;
            const bf16x8 a0 = ld_frag(&hS[l15 * 520 + k0 + quad * 8]);
            const bf16x8 a1 = ld_frag(&hS[(16 + l15) * 520 + k0 + quad * 8]);
#pragma unroll
            for (int et = 0; et < 4; et++) {
              acc2[0][et] = __builtin_amdgcn_mfma_f32_16x16x32_bf16(a0, fA[et], acc2[0][et], 0, 0, 0);
              acc2[1][et] = __builtin_amdgcn_mfma_f32_16x16x32_bf16(a1, fA[et], acc2[1][et], 0, 0, 0);
            }
            if (kk + 2 < 16) frag_issue(baseW, ((kk + 2 + phase) & 15) * 32, fA);
          }
          {
            const int k0 = ((kk + 1 + phase) & 15) * 32;
            const bf16x8 a0 = ld_frag(&hS[l15 * 520 + k0 + quad * 8]);
            const bf16x8 a1 = ld_frag(&hS[(16 + l15) * 520 + k0 + quad * 8]);
#pragma unroll
            for (int et = 0; et < 4; et++) {
              acc2[0][et] = __builtin_amdgcn_mfma_f32_16x16x32_bf16(a0, fB[et], acc2[0][et], 0, 0, 0);
              acc2[1][et] = __builtin_amdgcn_mfma_f32_16x16x32_bf16(a1, fB[et], acc2[1][et], 0, 0, 0);
            }
            if (kk + 3 < 16) frag_issue(baseW, ((kk + 3 + phase) & 15) * 32, fB);
          }
        }
      }

      // ---- masked online softmax over the 32 time rows of this pass ----
      bool ok[2][4];
#pragma unroll
      for (int mt = 0; mt < 2; mt++)
#pragma unroll
        for (int r = 0; r < 4; r++)
          ok[mt][r] = (r0 + mt * 16 + quad * 4 + r) < nvalid;

#pragma unroll
      for (int et = 0; et < 4; et++) {
        const int e = wbase + et * 16 + l15;
        float v[2][4];
        float lm = -1e30f;
#pragma unroll
        for (int mt = 0; mt < 2; mt++)
#pragma unroll
          for (int r = 0; r < 4; r++) {
            v[mt][r] = ok[mt][r] ? acc2[mt][et][r] : -1e30f;
            lm = fmaxf(lm, v[mt][r]);
          }
        lm = fmaxf(lm, __shfl_xor(lm, 16));
        lm = fmaxf(lm, __shfl_xor(lm, 32));
        float ls = 0.f, lo = 0.f;
#pragma unroll
        for (int mt = 0; mt < 2; mt++)
#pragma unroll
          for (int r = 0; r < 4; r++) {
            const float p  = __expf(v[mt][r] - lm);
            const float ev = bf2f(encA[(mt * 16 + quad * 4 + r) * 520 + e]);
            ls += p;
            lo += p * ev;
          }
        ls += __shfl_xor(ls, 16); ls += __shfl_xor(ls, 32);
        lo += __shfl_xor(lo, 16); lo += __shfl_xor(lo, 32);
        const float Mn = fmaxf(stM[et], lm);
        const float sc = __expf(stM[et] - Mn);
        const float st = __expf(lm - Mn);
        stS[et] = stS[et] * sc + ls * st;
        stO[et] = stO[et] * sc + lo * st;
        stM[et] = Mn;
      }
      __syncthreads();
    }

    if (quad == 0) {
      const size_t base = ((size_t)b * C + c) * EE;
#pragma unroll
      for (int et = 0; et < 4; et++) {
        const int e = wbase + et * 16 + l15;
        pm[base + e] = stM[et];
        ps[base + e] = stS[et];
        po[base + e] = stO[et];
      }
    }
  }
}

// ---------------- combine over chunks (parallelized: 8 e-slabs x 4 c-groups) ----------------
__global__ __launch_bounds__(256) void attn_combine(
    const float* __restrict__ pm, const float* __restrict__ ps,
    const float* __restrict__ po, const int* __restrict__ lens,
    float* __restrict__ out, int C, int Lc)
{
  const int b  = blockIdx.y;
  const int e  = blockIdx.x * 64 + (threadIdx.x & 63);
  const int g  = threadIdx.x >> 6;  // c-group 0..3
  const int n  = lens[b];
  const int cmax = min(C, (n + Lc - 1) / Lc);

  float M = -1e30f, S = 0.f, O = 0.f;
  for (int c = g; c < cmax; c += 4) {
    const size_t base = ((size_t)b * C + c) * EE;
    const float m = pm[base + e];
    const float s = ps[base + e];
    const float o = po[base + e];
    const float Mn  = fmaxf(M, m);
    const float sc0 = __expf(M - Mn);
    const float sc1 = __expf(m - Mn);
    S = S * sc0 + s * sc1;
    O = O * sc0 + o * sc1;
    M = Mn;
  }

  __shared__ float sM[4][64], sS[4][64], sO[4][64];
  sM[g][threadIdx.x & 63] = M;
  sS[g][threadIdx.x & 63] = S;
  sO[g][threadIdx.x & 63] = O;
  __syncthreads();

  if (g == 0) {
    const int le = threadIdx.x & 63;
    float Mt = sM[0][le], St = sS[0][le], Ot = sO[0][le];
#pragma unroll
    for (int gg = 1; gg < 4; gg++) {
      const float m = sM[gg][le];
      const float Mn  = fmaxf(Mt, m);
      const float sc0 = __expf(Mt - Mn);
      const float sc1 = __expf(m - Mn);
      St = St * sc0 + sS[gg][le] * sc1;
      Ot = Ot * sc0 + sO[gg][le] * sc1;
      Mt = Mn;
    }
    out[(size_t)b * EE + e] = Ot / St;  // St > 0: c=0 always valid (lengths >= 1)
  }
}

extern "C" void kernel_launch(void* const* d_in, const int* in_sizes, int n_in,
                              void* d_out, int out_size, void* d_ws, size_t ws_size,
                              hipStream_t stream) {
  const float* enc  = (const float*)d_in[0];
  const int*   lens = (const int*)d_in[1];
  const float* Wh   = (const float*)d_in[2];
  const float* bh   = (const float*)d_in[3];
  const float* Wc   = (const float*)d_in[4];
  float* out = (float*)d_out;

  const size_t wbytes = (size_t)512 * 512 * sizeof(unsigned short);
  int C = 64;  // Lc=32 -> one 32-row pass per item
  while (C > 8 && ws_size < (size_t)3 * BB * C * EE * sizeof(float) + 2 * wbytes + 64)
    C >>= 1;
  const int Lc = LL / C;

  float* pm = (float*)d_ws;
  float* ps = pm + (size_t)BB * C * EE;
  float* po = ps + (size_t)BB * C * EE;
  unsigned short* WhT = (unsigned short*)(po + (size_t)BB * C * EE);
  unsigned short* WcT = WhT + (size_t)512 * 512;
  int* q = (int*)(WcT + (size_t)512 * 512);

  prep_w<<<dim3(64, 2), 256, 0, stream>>>(Wh, Wc, WhT, WcT, q);
  attn_main<<<dim3(512), 512, 0, stream>>>(enc, lens, WhT, bh, WcT, pm, ps, po, q, C, Lc);
  attn_combine<<<dim3(8, BB), 256, 0, stream>>>(pm, ps, po, lens, out, C, Lc);
}

// Round 2
// 366.641 us; speedup vs baseline: 1.0083x; 1.0083x over previous
//
#include <hip/hip_runtime.h>
#include <math.h>

#define BB 32
#define LL 2048
#define EE 512
#define HH 512

typedef __bf16 bf16_t;
typedef bf16_t bf16x8 __attribute__((ext_vector_type(8)));
typedef float f32x4 __attribute__((ext_vector_type(4)));
typedef unsigned short u16x8 __attribute__((ext_vector_type(8)));

__device__ __forceinline__ unsigned short f2bf(float f) {
  unsigned int u = __builtin_bit_cast(unsigned int, f);
  unsigned int r = (u + 0x7FFFu + ((u >> 16) & 1u)) >> 16;  // RNE
  return (unsigned short)r;
}
__device__ __forceinline__ float bf2f(unsigned short s) {
  unsigned int u = ((unsigned int)s) << 16;
  return __builtin_bit_cast(float, u);
}
__device__ __forceinline__ bf16x8 ld_frag(const unsigned short* p) {
  u16x8 raw = *(const u16x8*)p;
  return __builtin_bit_cast(bf16x8, raw);
}
__device__ __forceinline__ float tanh_fast(float x) {
  x = fminf(fmaxf(x, -15.f), 15.f);
  float e2 = __expf(2.f * x);
  return (e2 - 1.f) / (e2 + 1.f);
}

// load the 4 A/B weight fragments (one 64-row x 32-k window) DIRECTLY global->reg
// in MFMA fragment layout. Each frag = 16 rows x 64B contiguous; weights (1MB bf16
// total) are L2-resident, and each element feeds exactly ONE MFMA, so LDS staging
// was a pure write+read round-trip (and the 64KB slab capped us at 1 block/CU).
__device__ __forceinline__ void frag_issue(const unsigned short* __restrict__ g,
                                           int k0, bf16x8 f[4]) {
#pragma unroll
  for (int i = 0; i < 4; i++) f[i] = ld_frag(g + (size_t)i * 16 * 512 + k0);
}

// ---------------- prep: transpose + fp32->bf16 convert of Wh, Wc; init work queue ----------------
__global__ __launch_bounds__(256) void prep_w(
    const float* __restrict__ Wh, const float* __restrict__ Wc,
    unsigned short* __restrict__ WhT, unsigned short* __restrict__ WcT,
    int* __restrict__ q)
{
  if (blockIdx.x == 0 && blockIdx.y == 0 && threadIdx.x == 0) *q = 0;
  const float* src = blockIdx.y ? Wc : Wh;
  unsigned short* dst = blockIdx.y ? WcT : WhT;
  const int tr = (blockIdx.x >> 3) * 64;
  const int tc = (blockIdx.x & 7) * 64;
  const int tid = threadIdx.x;
  __shared__ float tile[64][65];
  for (int i = tid; i < 64 * 16; i += 256) {
    const int r = i >> 4, c4 = (i & 15) << 2;
    const float4 v = *(const float4*)(src + (size_t)(tr + r) * 512 + tc + c4);
    tile[r][c4 + 0] = v.x; tile[r][c4 + 1] = v.y;
    tile[r][c4 + 2] = v.z; tile[r][c4 + 3] = v.w;
  }
  __syncthreads();
  for (int i = tid; i < 64 * 16; i += 256) {
    const int r = i >> 4, c4 = (i & 15) << 2;
    ushort4 pk;
    pk.x = f2bf(tile[c4 + 0][r]); pk.y = f2bf(tile[c4 + 1][r]);
    pk.z = f2bf(tile[c4 + 2][r]); pk.w = f2bf(tile[c4 + 3][r]);
    *(ushort4*)(dst + (size_t)(tc + r) * 512 + tr + c4) = pk;
  }
}

// ---------------- main: persistent blocks pop (b,c) items; k-loop rotated per (item,wave) ----------------
// LDS = encA + hS + bh ~= 68.6 KB -> 2 blocks/CU resident.
// Register budget at 4 waves/EU is 128/wave (unified VGPR+AGPR). To fit without
// spills, GEMM1 and GEMM2 SHARE one accumulator array (acc1 is dead after the
// tanh/pack phase), and the softmax avoids spill-prone temp arrays.
__global__ __launch_bounds__(512, 4) void attn_main(
    const float* __restrict__ enc, const int* __restrict__ lens,
    const unsigned short* __restrict__ WhT, const float* __restrict__ bh,
    const unsigned short* __restrict__ WcT,
    float* __restrict__ pm, float* __restrict__ ps, float* __restrict__ po,
    int* __restrict__ q, int C, int Lc)
{
  const int tid  = threadIdx.x;
  const int wave = tid >> 6;       // 0..7
  const int lane = tid & 63;
  const int quad = lane >> 4;
  const int l15  = lane & 15;
  const int wbase = wave * 64;     // wave's 64-wide h-slab (GEMM1) / e-slab (GEMM2)

  __shared__ __align__(16) unsigned short encA[32 * 520];  // 33.3 KB
  __shared__ __align__(16) unsigned short hS[32 * 520];    // 33.3 KB
  __shared__ __align__(16) float bhS[512];
  __shared__ int itemS;

  bhS[tid] = bh[tid];
  const int nitems = 32 * C;

#pragma unroll 1
  for (;;) {
    __syncthreads();                       // protect itemS + LDS from previous item
    if (tid == 0) itemS = atomicAdd(q, 1);
    __syncthreads();
    const int item = itemS;
    if (item >= nitems) break;            // uniform across block
    const int b = item & 31;
    const int c = item >> 5;
    const int n = lens[b];
    const int l0 = c * Lc;
    const int nvalid = min(n - l0, Lc);
    if (nvalid <= 0) continue;

    const int phase = (item + wave) & 15;  // k-window de-phasing across waves/items

    float stM[4], stS[4], stO[4];
#pragma unroll
    for (int et = 0; et < 4; et++) { stM[et] = -1e30f; stS[et] = 0.f; stO[et] = 0.f; }

    // single accumulator array shared by both GEMMs (live ranges do not overlap)
    f32x4 acc[8];

#pragma unroll 1
    for (int r0 = 0; r0 < nvalid; r0 += 32) {
      // ---- stage enc tile -> bf16 LDS (one copy shared by 8 waves) ----
      const float* encRow = enc + ((size_t)b * LL + l0 + r0) * EE;
      for (int i = tid; i < 32 * 128; i += 512) {
        const int m = i >> 7, e4 = (i & 127) << 2;
        const float4 v = *(const float4*)(encRow + (size_t)m * EE + e4);
        ushort4 pk;
        pk.x = f2bf(v.x); pk.y = f2bf(v.y); pk.z = f2bf(v.z); pk.w = f2bf(v.w);
        *(ushort4*)&encA[m * 520 + e4] = pk;
      }
      __syncthreads();

      // ================= GEMM1: hT[64 x 32] per wave = WhT @ encT =================
      // acc[t*2 + mt]
#pragma unroll
      for (int i = 0; i < 8; i++) acc[i] = (f32x4){0.f, 0.f, 0.f, 0.f};
      {
        const unsigned short* baseW = WhT + (size_t)(wbase + l15) * 512 + quad * 8;
        bf16x8 fA[4], fB[4];
        frag_issue(baseW, ((0 + phase) & 15) * 32, fA);
        frag_issue(baseW, ((1 + phase) & 15) * 32, fB);
#pragma unroll 1
        for (int kk = 0; kk < 16; kk += 2) {
          {
            const int k0 = ((kk + phase) & 15) * 32;
            const bf16x8 b0 = ld_frag(&encA[l15 * 520 + k0 + quad * 8]);
            const bf16x8 b1 = ld_frag(&encA[(16 + l15) * 520 + k0 + quad * 8]);
#pragma unroll
            for (int t = 0; t < 4; t++) {
              acc[t * 2 + 0] = __builtin_amdgcn_mfma_f32_16x16x32_bf16(fA[t], b0, acc[t * 2 + 0], 0, 0, 0);
              acc[t * 2 + 1] = __builtin_amdgcn_mfma_f32_16x16x32_bf16(fA[t], b1, acc[t * 2 + 1], 0, 0, 0);
            }
            if (kk + 2 < 16) frag_issue(baseW, ((kk + 2 + phase) & 15) * 32, fA);
          }
          {
            const int k0 = ((kk + 1 + phase) & 15) * 32;
            const bf16x8 b0 = ld_frag(&encA[l15 * 520 + k0 + quad * 8]);
            const bf16x8 b1 = ld_frag(&encA[(16 + l15) * 520 + k0 + quad * 8]);
#pragma unroll
            for (int t = 0; t < 4; t++) {
              acc[t * 2 + 0] = __builtin_amdgcn_mfma_f32_16x16x32_bf16(fB[t], b0, acc[t * 2 + 0], 0, 0, 0);
              acc[t * 2 + 1] = __builtin_amdgcn_mfma_f32_16x16x32_bf16(fB[t], b1, acc[t * 2 + 1], 0, 0, 0);
            }
            if (kk + 3 < 16) frag_issue(baseW, ((kk + 3 + phase) & 15) * 32, fB);
          }
        }
      }

      // ---- bias + tanh, pack 4 consecutive h -> one 8B LDS write of h[m][h] ----
#pragma unroll
      for (int t = 0; t < 4; t++) {
        const f32x4 bv = *(const f32x4*)&bhS[wbase + t * 16 + quad * 4];
#pragma unroll
        for (int mt = 0; mt < 2; mt++) {
          ushort4 pk;
          pk.x = f2bf(tanh_fast(acc[t * 2 + mt][0] + bv[0]));
          pk.y = f2bf(tanh_fast(acc[t * 2 + mt][1] + bv[1]));
          pk.z = f2bf(tanh_fast(acc[t * 2 + mt][2] + bv[2]));
          pk.w = f2bf(tanh_fast(acc[t * 2 + mt][3] + bv[3]));
          *(ushort4*)&hS[(mt * 16 + l15) * 520 + wbase + t * 16 + quad * 4] = pk;
        }
      }
      __syncthreads();

      // ================= GEMM2: logits[32 x 64] per wave = h @ WcT-slab =================
      // acc[mt*4 + et]
#pragma unroll
      for (int i = 0; i < 8; i++) acc[i] = (f32x4){0.f, 0.f, 0.f, 0.f};
      {
        const unsigned short* baseW = WcT + (size_t)(wbase + l15) * 512 + quad * 8;
        bf16x8 fA[4], fB[4];
        frag_issue(baseW, ((0 + phase) & 15) * 32, fA);
        frag_issue(baseW, ((1 + phase) & 15) * 32, fB);
#pragma unroll 1
        for (int kk = 0; kk < 16; kk += 2) {
          {
            const int k0 = ((kk + phase) & 15) * 32;
            const bf16x8 a0 = ld_frag(&hS[l15 * 520 + k0 + quad * 8]);
            const bf16x8 a1 = ld_frag(&hS[(16 + l15) * 520 + k0 + quad * 8]);
#pragma unroll
            for (int et = 0; et < 4; et++) {
              acc[0 * 4 + et] = __builtin_amdgcn_mfma_f32_16x16x32_bf16(a0, fA[et], acc[0 * 4 + et], 0, 0, 0);
              acc[1 * 4 + et] = __builtin_amdgcn_mfma_f32_16x16x32_bf16(a1, fA[et], acc[1 * 4 + et], 0, 0, 0);
            }
            if (kk + 2 < 16) frag_issue(baseW, ((kk + 2 + phase) & 15) * 32, fA);
          }
          {
            const int k0 = ((kk + 1 + phase) & 15) * 32;
            const bf16x8 a0 = ld_frag(&hS[l15 * 520 + k0 + quad * 8]);
            const bf16x8 a1 = ld_frag(&hS[(16 + l15) * 520 + k0 + quad * 8]);
#pragma unroll
            for (int et = 0; et < 4; et++) {
              acc[0 * 4 + et] = __builtin_amdgcn_mfma_f32_16x16x32_bf16(a0, fB[et], acc[0 * 4 + et], 0, 0, 0);
              acc[1 * 4 + et] = __builtin_amdgcn_mfma_f32_16x16x32_bf16(a1, fB[et], acc[1 * 4 + et], 0, 0, 0);
            }
            if (kk + 3 < 16) frag_issue(baseW, ((kk + 3 + phase) & 15) * 32, fB);
          }
        }
      }

      // ---- masked online softmax over the 32 time rows of this pass ----
      // mask recomputed inline (2 VALU ops) instead of stored arrays: keeps
      // register pressure under the 128/wave budget.
#pragma unroll
      for (int et = 0; et < 4; et++) {
        const int e = wbase + et * 16 + l15;
        float lm = -1e30f;
#pragma unroll
        for (int mt = 0; mt < 2; mt++)
#pragma unroll
          for (int r = 0; r < 4; r++) {
            const float vv = (r0 + mt * 16 + quad * 4 + r) < nvalid ? acc[mt * 4 + et][r] : -1e30f;
            lm = fmaxf(lm, vv);
          }
        lm = fmaxf(lm, __shfl_xor(lm, 16));
        lm = fmaxf(lm, __shfl_xor(lm, 32));
        float ls = 0.f, lo = 0.f;
#pragma unroll
        for (int mt = 0; mt < 2; mt++)
#pragma unroll
          for (int r = 0; r < 4; r++) {
            const float vv = (r0 + mt * 16 + quad * 4 + r) < nvalid ? acc[mt * 4 + et][r] : -1e30f;
            const float p  = __expf(vv - lm);
            const float ev = bf2f(encA[(mt * 16 + quad * 4 + r) * 520 + e]);
            ls += p;
            lo += p * ev;
          }
        ls += __shfl_xor(ls, 16); ls += __shfl_xor(ls, 32);
        lo += __shfl_xor(lo, 16); lo += __shfl_xor(lo, 32);
        const float Mn = fmaxf(stM[et], lm);
        const float sc = __expf(stM[et] - Mn);
        const float st = __expf(lm - Mn);
        stS[et] = stS[et] * sc + ls * st;
        stO[et] = stO[et] * sc + lo * st;
        stM[et] = Mn;
      }
      __syncthreads();
    }

    if (quad == 0) {
      const size_t base = ((size_t)b * C + c) * EE;
#pragma unroll
      for (int et = 0; et < 4; et++) {
        const int e = wbase + et * 16 + l15;
        pm[base + e] = stM[et];
        ps[base + e] = stS[et];
        po[base + e] = stO[et];
      }
    }
  }
}

// ---------------- combine over chunks (parallelized: 8 e-slabs x 4 c-groups) ----------------
__global__ __launch_bounds__(256) void attn_combine(
    const float* __restrict__ pm, const float* __restrict__ ps,
    const float* __restrict__ po, const int* __restrict__ lens,
    float* __restrict__ out, int C, int Lc)
{
  const int b  = blockIdx.y;
  const int e  = blockIdx.x * 64 + (threadIdx.x & 63);
  const int g  = threadIdx.x >> 6;  // c-group 0..3
  const int n  = lens[b];
  const int cmax = min(C, (n + Lc - 1) / Lc);

  float M = -1e30f, S = 0.f, O = 0.f;
  for (int c = g; c < cmax; c += 4) {
    const size_t base = ((size_t)b * C + c) * EE;
    const float m = pm[base + e];
    const float s = ps[base + e];
    const float o = po[base + e];
    const float Mn  = fmaxf(M, m);
    const float sc0 = __expf(M - Mn);
    const float sc1 = __expf(m - Mn);
    S = S * sc0 + s * sc1;
    O = O * sc0 + o * sc1;
    M = Mn;
  }

  __shared__ float sM[4][64], sS[4][64], sO[4][64];
  sM[g][threadIdx.x & 63] = M;
  sS[g][threadIdx.x & 63] = S;
  sO[g][threadIdx.x & 63] = O;
  __syncthreads();

  if (g == 0) {
    const int le = threadIdx.x & 63;
    float Mt = sM[0][le], St = sS[0][le], Ot = sO[0][le];
#pragma unroll
    for (int gg = 1; gg < 4; gg++) {
      const float m = sM[gg][le];
      const float Mn  = fmaxf(Mt, m);
      const float sc0 = __expf(Mt - Mn);
      const float sc1 = __expf(m - Mn);
      St = St * sc0 + sS[gg][le] * sc1;
      Ot = Ot * sc0 + sO[gg][le] * sc1;
      Mt = Mn;
    }
    out[(size_t)b * EE + e] = Ot / St;  // St > 0: c=0 always valid (lengths >= 1)
  }
}

extern "C" void kernel_launch(void* const* d_in, const int* in_sizes, int n_in,
                              void* d_out, int out_size, void* d_ws, size_t ws_size,
                              hipStream_t stream) {
  const float* enc  = (const float*)d_in[0];
  const int*   lens = (const int*)d_in[1];
  const float* Wh   = (const float*)d_in[2];
  const float* bh   = (const float*)d_in[3];
  const float* Wc   = (const float*)d_in[4];
  float* out = (float*)d_out;

  const size_t wbytes = (size_t)512 * 512 * sizeof(unsigned short);
  int C = 64;  // Lc=32 -> one 32-row pass per item
  while (C > 8 && ws_size < (size_t)3 * BB * C * EE * sizeof(float) + 2 * wbytes + 64)
    C >>= 1;
  const int Lc = LL / C;

  float* pm = (float*)d_ws;
  float* ps = pm + (size_t)BB * C * EE;
  float* po = ps + (size_t)BB * C * EE;
  unsigned short* WhT = (unsigned short*)(po + (size_t)BB * C * EE);
  unsigned short* WcT = WhT + (size_t)512 * 512;
  int* q = (int*)(WcT + (size_t)512 * 512);

  prep_w<<<dim3(64, 2), 256, 0, stream>>>(Wh, Wc, WhT, WcT, q);
  attn_main<<<dim3(512), 512, 0, stream>>>(enc, lens, WhT, bh, WcT, pm, ps, po, q, C, Lc);
  attn_combine<<<dim3(8, BB), 256, 0, stream>>>(pm, ps, po, lens, out, C, Lc);
}

// Round 3
// 353.382 us; speedup vs baseline: 1.0461x; 1.0375x over previous
//
#include <hip/hip_runtime.h>
#include <math.h>

#define BB 32
#define LL 2048
#define EE 512
#define HH 512

typedef __bf16 bf16_t;
typedef bf16_t bf16x8 __attribute__((ext_vector_type(8)));
typedef float f32x4 __attribute__((ext_vector_type(4)));
typedef unsigned short u16x8 __attribute__((ext_vector_type(8)));

__device__ __forceinline__ unsigned short f2bf(float f) {
  unsigned int u = __builtin_bit_cast(unsigned int, f);
  unsigned int r = (u + 0x7FFFu + ((u >> 16) & 1u)) >> 16;  // RNE
  return (unsigned short)r;
}
__device__ __forceinline__ float bf2f(unsigned short s) {
  unsigned int u = ((unsigned int)s) << 16;
  return __builtin_bit_cast(float, u);
}
__device__ __forceinline__ bf16x8 ld_frag(const unsigned short* p) {
  u16x8 raw = *(const u16x8*)p;
  return __builtin_bit_cast(bf16x8, raw);
}
__device__ __forceinline__ float tanh_fast(float x) {
  x = fminf(fmaxf(x, -15.f), 15.f);
  float e2 = __expf(2.f * x);
  return (e2 - 1.f) / (e2 + 1.f);
}

// load the 4 A/B weight fragments (one 64-row x 32-k window) DIRECTLY global->reg
// in MFMA fragment layout. Weights (1MB bf16 total) are L2-resident and each
// element feeds exactly one MFMA -> LDS staging would be a pure round-trip.
__device__ __forceinline__ void frag_issue(const unsigned short* __restrict__ g,
                                           int k0, bf16x8 f[4]) {
#pragma unroll
  for (int i = 0; i < 4; i++) f[i] = ld_frag(g + (size_t)i * 16 * 512 + k0);
}

// ---------------- prep: transpose + fp32->bf16 convert of Wh, Wc; init work queue ----------------
__global__ __launch_bounds__(256) void prep_w(
    const float* __restrict__ Wh, const float* __restrict__ Wc,
    unsigned short* __restrict__ WhT, unsigned short* __restrict__ WcT,
    int* __restrict__ q)
{
  if (blockIdx.x == 0 && blockIdx.y == 0 && threadIdx.x == 0) *q = 0;
  const float* src = blockIdx.y ? Wc : Wh;
  unsigned short* dst = blockIdx.y ? WcT : WhT;
  const int tr = (blockIdx.x >> 3) * 64;
  const int tc = (blockIdx.x & 7) * 64;
  const int tid = threadIdx.x;
  __shared__ float tile[64][65];
  for (int i = tid; i < 64 * 16; i += 256) {
    const int r = i >> 4, c4 = (i & 15) << 2;
    const float4 v = *(const float4*)(src + (size_t)(tr + r) * 512 + tc + c4);
    tile[r][c4 + 0] = v.x; tile[r][c4 + 1] = v.y;
    tile[r][c4 + 2] = v.z; tile[r][c4 + 3] = v.w;
  }
  __syncthreads();
  for (int i = tid; i < 64 * 16; i += 256) {
    const int r = i >> 4, c4 = (i & 15) << 2;
    ushort4 pk;
    pk.x = f2bf(tile[c4 + 0][r]); pk.y = f2bf(tile[c4 + 1][r]);
    pk.z = f2bf(tile[c4 + 2][r]); pk.w = f2bf(tile[c4 + 3][r]);
    *(ushort4*)(dst + (size_t)(tc + r) * 512 + tr + c4) = pk;
  }
}

// ---------------- main: 256-thread blocks (4 waves), each wave covers TWO 64-col slabs ----------------
// LDS ~68.6 KB/block -> 2 blocks/CU by LDS; __launch_bounds__(256,2) -> 256 regs/wave
// (spill-free budget, same as the proven R0 build). Same 8 waves/CU as the 512-thread
// 1-block config, but in TWO independent barrier domains: while one block sits at its
// stage/pack barriers, the other block's waves feed the MFMA pipe.
__global__ __launch_bounds__(256, 2) void attn_main(
    const float* __restrict__ enc, const int* __restrict__ lens,
    const unsigned short* __restrict__ WhT, const float* __restrict__ bh,
    const unsigned short* __restrict__ WcT,
    float* __restrict__ pm, float* __restrict__ ps, float* __restrict__ po,
    int* __restrict__ q, int C, int Lc)
{
  const int tid  = threadIdx.x;
  const int wave = tid >> 6;       // 0..3
  const int lane = tid & 63;
  const int quad = lane >> 4;
  const int l15  = lane & 15;

  __shared__ __align__(16) unsigned short encA[32 * 520];  // 33.3 KB
  __shared__ __align__(16) unsigned short hS[32 * 520];    // 33.3 KB
  __shared__ __align__(16) float bhS[512];
  __shared__ int itemS;

  bhS[tid] = bh[tid];
  bhS[tid + 256] = bh[tid + 256];
  const int nitems = 32 * C;

#pragma unroll 1
  for (;;) {
    __syncthreads();                       // protect itemS + LDS from previous item
    if (tid == 0) itemS = atomicAdd(q, 1);
    __syncthreads();
    const int item = itemS;
    if (item >= nitems) break;            // uniform across block
    const int b = item & 31;
    const int c = item >> 5;
    const int n = lens[b];
    const int l0 = c * Lc;
    const int nvalid = min(n - l0, Lc);
    if (nvalid <= 0) continue;

    float stM[2][4], stS[2][4], stO[2][4];
#pragma unroll
    for (int s = 0; s < 2; s++)
#pragma unroll
      for (int et = 0; et < 4; et++) { stM[s][et] = -1e30f; stS[s][et] = 0.f; stO[s][et] = 0.f; }

#pragma unroll 1
    for (int r0 = 0; r0 < nvalid; r0 += 32) {
      // ---- stage enc tile -> bf16 LDS (one copy shared by 4 waves) ----
      const float* encRow = enc + ((size_t)b * LL + l0 + r0) * EE;
      for (int i = tid; i < 32 * 128; i += 256) {
        const int m = i >> 7, e4 = (i & 127) << 2;
        const float4 v = *(const float4*)(encRow + (size_t)m * EE + e4);
        ushort4 pk;
        pk.x = f2bf(v.x); pk.y = f2bf(v.y); pk.z = f2bf(v.z); pk.w = f2bf(v.w);
        *(ushort4*)&encA[m * 520 + e4] = pk;
      }
      __syncthreads();

      // ================= GEMM1 (both slabs): hT[64 x 32] = WhT-slab @ encT =================
#pragma unroll
      for (int s = 0; s < 2; s++) {
        const int wbase = (wave * 2 + s) * 64;
        const int phase = (item + wave * 2 + s) & 15;  // k-window de-phasing
        f32x4 acc[8];                                   // acc[t*2+mt]
#pragma unroll
        for (int i = 0; i < 8; i++) acc[i] = (f32x4){0.f, 0.f, 0.f, 0.f};
        {
          const unsigned short* baseW = WhT + (size_t)(wbase + l15) * 512 + quad * 8;
          bf16x8 fA[4], fB[4];
          frag_issue(baseW, ((0 + phase) & 15) * 32, fA);
          frag_issue(baseW, ((1 + phase) & 15) * 32, fB);
#pragma unroll 1
          for (int kk = 0; kk < 16; kk += 2) {
            {
              const int k0 = ((kk + phase) & 15) * 32;
              const bf16x8 b0 = ld_frag(&encA[l15 * 520 + k0 + quad * 8]);
              const bf16x8 b1 = ld_frag(&encA[(16 + l15) * 520 + k0 + quad * 8]);
#pragma unroll
              for (int t = 0; t < 4; t++) {
                acc[t * 2 + 0] = __builtin_amdgcn_mfma_f32_16x16x32_bf16(fA[t], b0, acc[t * 2 + 0], 0, 0, 0);
                acc[t * 2 + 1] = __builtin_amdgcn_mfma_f32_16x16x32_bf16(fA[t], b1, acc[t * 2 + 1], 0, 0, 0);
              }
              if (kk + 2 < 16) frag_issue(baseW, ((kk + 2 + phase) & 15) * 32, fA);
            }
            {
              const int k0 = ((kk + 1 + phase) & 15) * 32;
              const bf16x8 b0 = ld_frag(&encA[l15 * 520 + k0 + quad * 8]);
              const bf16x8 b1 = ld_frag(&encA[(16 + l15) * 520 + k0 + quad * 8]);
#pragma unroll
              for (int t = 0; t < 4; t++) {
                acc[t * 2 + 0] = __builtin_amdgcn_mfma_f32_16x16x32_bf16(fB[t], b0, acc[t * 2 + 0], 0, 0, 0);
                acc[t * 2 + 1] = __builtin_amdgcn_mfma_f32_16x16x32_bf16(fB[t], b1, acc[t * 2 + 1], 0, 0, 0);
              }
              if (kk + 3 < 16) frag_issue(baseW, ((kk + 3 + phase) & 15) * 32, fB);
            }
          }
        }

        // ---- bias + tanh, pack 4 consecutive h -> one 8B LDS write of h[m][h] ----
#pragma unroll
        for (int t = 0; t < 4; t++) {
          const f32x4 bv = *(const f32x4*)&bhS[wbase + t * 16 + quad * 4];
#pragma unroll
          for (int mt = 0; mt < 2; mt++) {
            ushort4 pk;
            pk.x = f2bf(tanh_fast(acc[t * 2 + mt][0] + bv[0]));
            pk.y = f2bf(tanh_fast(acc[t * 2 + mt][1] + bv[1]));
            pk.z = f2bf(tanh_fast(acc[t * 2 + mt][2] + bv[2]));
            pk.w = f2bf(tanh_fast(acc[t * 2 + mt][3] + bv[3]));
            *(ushort4*)&hS[(mt * 16 + l15) * 520 + wbase + t * 16 + quad * 4] = pk;
          }
        }
      }
      __syncthreads();

      // ================= GEMM2 (both slabs): logits[32 x 64] = h @ WcT-slab =================
#pragma unroll
      for (int s = 0; s < 2; s++) {
        const int wbase = (wave * 2 + s) * 64;
        const int phase = (item + wave * 2 + s) & 15;
        f32x4 acc[8];                                   // acc[mt*4+et]
#pragma unroll
        for (int i = 0; i < 8; i++) acc[i] = (f32x4){0.f, 0.f, 0.f, 0.f};
        {
          const unsigned short* baseW = WcT + (size_t)(wbase + l15) * 512 + quad * 8;
          bf16x8 fA[4], fB[4];
          frag_issue(baseW, ((0 + phase) & 15) * 32, fA);
          frag_issue(baseW, ((1 + phase) & 15) * 32, fB);
#pragma unroll 1
          for (int kk = 0; kk < 16; kk += 2) {
            {
              const int k0 = ((kk + phase) & 15) * 32;
              const bf16x8 a0 = ld_frag(&hS[l15 * 520 + k0 + quad * 8]);
              const bf16x8 a1 = ld_frag(&hS[(16 + l15) * 520 + k0 + quad * 8]);
#pragma unroll
              for (int et = 0; et < 4; et++) {
                acc[0 * 4 + et] = __builtin_amdgcn_mfma_f32_16x16x32_bf16(a0, fA[et], acc[0 * 4 + et], 0, 0, 0);
                acc[1 * 4 + et] = __builtin_amdgcn_mfma_f32_16x16x32_bf16(a1, fA[et], acc[1 * 4 + et], 0, 0, 0);
              }
              if (kk + 2 < 16) frag_issue(baseW, ((kk + 2 + phase) & 15) * 32, fA);
            }
            {
              const int k0 = ((kk + 1 + phase) & 15) * 32;
              const bf16x8 a0 = ld_frag(&hS[l15 * 520 + k0 + quad * 8]);
              const bf16x8 a1 = ld_frag(&hS[(16 + l15) * 520 + k0 + quad * 8]);
#pragma unroll
              for (int et = 0; et < 4; et++) {
                acc[0 * 4 + et] = __builtin_amdgcn_mfma_f32_16x16x32_bf16(a0, fB[et], acc[0 * 4 + et], 0, 0, 0);
                acc[1 * 4 + et] = __builtin_amdgcn_mfma_f32_16x16x32_bf16(a1, fB[et], acc[1 * 4 + et], 0, 0, 0);
              }
              if (kk + 3 < 16) frag_issue(baseW, ((kk + 3 + phase) & 15) * 32, fB);
            }
          }
        }

        // ---- masked online softmax for this slab's 64 e-cols ----
#pragma unroll
        for (int et = 0; et < 4; et++) {
          const int e = wbase + et * 16 + l15;
          float lm = -1e30f;
#pragma unroll
          for (int mt = 0; mt < 2; mt++)
#pragma unroll
            for (int r = 0; r < 4; r++) {
              const float vv = (r0 + mt * 16 + quad * 4 + r) < nvalid ? acc[mt * 4 + et][r] : -1e30f;
              lm = fmaxf(lm, vv);
            }
          lm = fmaxf(lm, __shfl_xor(lm, 16));
          lm = fmaxf(lm, __shfl_xor(lm, 32));
          float ls = 0.f, lo = 0.f;
#pragma unroll
          for (int mt = 0; mt < 2; mt++)
#pragma unroll
            for (int r = 0; r < 4; r++) {
              const float vv = (r0 + mt * 16 + quad * 4 + r) < nvalid ? acc[mt * 4 + et][r] : -1e30f;
              const float p  = __expf(vv - lm);
              const float ev = bf2f(encA[(mt * 16 + quad * 4 + r) * 520 + e]);
              ls += p;
              lo += p * ev;
            }
          ls += __shfl_xor(ls, 16); ls += __shfl_xor(ls, 32);
          lo += __shfl_xor(lo, 16); lo += __shfl_xor(lo, 32);
          const float Mn = fmaxf(stM[s][et], lm);
          const float sc = __expf(stM[s][et] - Mn);
          const float st = __expf(lm - Mn);
          stS[s][et] = stS[s][et] * sc + ls * st;
          stO[s][et] = stO[s][et] * sc + lo * st;
          stM[s][et] = Mn;
        }
      }
      __syncthreads();
    }

    if (quad == 0) {
      const size_t base = ((size_t)b * C + c) * EE;
#pragma unroll
      for (int s = 0; s < 2; s++)
#pragma unroll
        for (int et = 0; et < 4; et++) {
          const int e = (wave * 2 + s) * 64 + et * 16 + l15;
          pm[base + e] = stM[s][et];
          ps[base + e] = stS[s][et];
          po[base + e] = stO[s][et];
        }
    }
  }
}

// ---------------- combine over chunks (parallelized: 8 e-slabs x 4 c-groups) ----------------
__global__ __launch_bounds__(256) void attn_combine(
    const float* __restrict__ pm, const float* __restrict__ ps,
    const float* __restrict__ po, const int* __restrict__ lens,
    float* __restrict__ out, int C, int Lc)
{
  const int b  = blockIdx.y;
  const int e  = blockIdx.x * 64 + (threadIdx.x & 63);
  const int g  = threadIdx.x >> 6;  // c-group 0..3
  const int n  = lens[b];
  const int cmax = min(C, (n + Lc - 1) / Lc);

  float M = -1e30f, S = 0.f, O = 0.f;
  for (int c = g; c < cmax; c += 4) {
    const size_t base = ((size_t)b * C + c) * EE;
    const float m = pm[base + e];
    const float s = ps[base + e];
    const float o = po[base + e];
    const float Mn  = fmaxf(M, m);
    const float sc0 = __expf(M - Mn);
    const float sc1 = __expf(m - Mn);
    S = S * sc0 + s * sc1;
    O = O * sc0 + o * sc1;
    M = Mn;
  }

  __shared__ float sM[4][64], sS[4][64], sO[4][64];
  sM[g][threadIdx.x & 63] = M;
  sS[g][threadIdx.x & 63] = S;
  sO[g][threadIdx.x & 63] = O;
  __syncthreads();

  if (g == 0) {
    const int le = threadIdx.x & 63;
    float Mt = sM[0][le], St = sS[0][le], Ot = sO[0][le];
#pragma unroll
    for (int gg = 1; gg < 4; gg++) {
      const float m = sM[gg][le];
      const float Mn  = fmaxf(Mt, m);
      const float sc0 = __expf(Mt - Mn);
      const float sc1 = __expf(m - Mn);
      St = St * sc0 + sS[gg][le] * sc1;
      Ot = Ot * sc0 + sO[gg][le] * sc1;
      Mt = Mn;
    }
    out[(size_t)b * EE + e] = Ot / St;  // St > 0: c=0 always valid (lengths >= 1)
  }
}

extern "C" void kernel_launch(void* const* d_in, const int* in_sizes, int n_in,
                              void* d_out, int out_size, void* d_ws, size_t ws_size,
                              hipStream_t stream) {
  const float* enc  = (const float*)d_in[0];
  const int*   lens = (const int*)d_in[1];
  const float* Wh   = (const float*)d_in[2];
  const float* bh   = (const float*)d_in[3];
  const float* Wc   = (const float*)d_in[4];
  float* out = (float*)d_out;

  const size_t wbytes = (size_t)512 * 512 * sizeof(unsigned short);
  int C = 64;  // Lc=32 -> one 32-row pass per item
  while (C > 8 && ws_size < (size_t)3 * BB * C * EE * sizeof(float) + 2 * wbytes + 64)
    C >>= 1;
  const int Lc = LL / C;

  float* pm = (float*)d_ws;
  float* ps = pm + (size_t)BB * C * EE;
  float* po = ps + (size_t)BB * C * EE;
  unsigned short* WhT = (unsigned short*)(po + (size_t)BB * C * EE);
  unsigned short* WcT = WhT + (size_t)512 * 512;
  int* q = (int*)(WcT + (size_t)512 * 512);

  prep_w<<<dim3(64, 2), 256, 0, stream>>>(Wh, Wc, WhT, WcT, q);
  attn_main<<<dim3(512), 256, 0, stream>>>(enc, lens, WhT, bh, WcT, pm, ps, po, q, C, Lc);
  attn_combine<<<dim3(8, BB), 256, 0, stream>>>(pm, ps, po, lens, out, C, Lc);
}

// Round 4
// 313.467 us; speedup vs baseline: 1.1793x; 1.1273x over previous
//
#include <hip/hip_runtime.h>
#include <math.h>

#define BB 32
#define LL 2048
#define EE 512
#define HH 512

typedef __bf16 bf16_t;
typedef bf16_t bf16x8 __attribute__((ext_vector_type(8)));
typedef float f32x4 __attribute__((ext_vector_type(4)));
typedef unsigned short u16x8 __attribute__((ext_vector_type(8)));

__device__ __forceinline__ unsigned short f2bf(float f) {
  unsigned int u = __builtin_bit_cast(unsigned int, f);
  unsigned int r = (u + 0x7FFFu + ((u >> 16) & 1u)) >> 16;  // RNE
  return (unsigned short)r;
}
__device__ __forceinline__ float bf2f(unsigned short s) {
  unsigned int u = ((unsigned int)s) << 16;
  return __builtin_bit_cast(float, u);
}
__device__ __forceinline__ bf16x8 ld_frag(const unsigned short* p) {
  u16x8 raw = *(const u16x8*)p;
  return __builtin_bit_cast(bf16x8, raw);
}
__device__ __forceinline__ float tanh_fast(float x) {
  x = fminf(fmaxf(x, -15.f), 15.f);
  float e2 = __expf(2.f * x);
  return (e2 - 1.f) / (e2 + 1.f);
}

// load 4 weight fragments (64 rows x 32-k window) global->reg in MFMA layout.
__device__ __forceinline__ void frag_issue(const unsigned short* __restrict__ g,
                                           int k0, bf16x8 f[4]) {
#pragma unroll
  for (int i = 0; i < 4; i++) f[i] = ld_frag(g + (size_t)i * 16 * 512 + k0);
}

// one GEMM1 half-step: optional distance-3 prefetch into PFB, then 16 MFMAs
// consuming buffer F (window W). All frag-buffer indices are compile-time.
#define G1_HALF(F, W, PF, PFB) do {                                             \
    if (PF) frag_issue(baseW, (((W) + 3 + phase) & 15) * 32, PFB);              \
    const int k0_ = (((W) + phase) & 15) * 32;                                  \
    const bf16x8 b0_ = ld_frag(&encA[(l15     ) * 520 + k0_ + quad * 8]);       \
    const bf16x8 b1_ = ld_frag(&encA[(16 + l15) * 520 + k0_ + quad * 8]);       \
    const bf16x8 b2_ = ld_frag(&encA[(32 + l15) * 520 + k0_ + quad * 8]);       \
    const bf16x8 b3_ = ld_frag(&encA[(48 + l15) * 520 + k0_ + quad * 8]);       \
    _Pragma("unroll")                                                           \
    for (int t_ = 0; t_ < 4; t_++) {                                            \
      acc[t_ * 4 + 0] = __builtin_amdgcn_mfma_f32_16x16x32_bf16(F[t_], b0_, acc[t_ * 4 + 0], 0, 0, 0); \
      acc[t_ * 4 + 1] = __builtin_amdgcn_mfma_f32_16x16x32_bf16(F[t_], b1_, acc[t_ * 4 + 1], 0, 0, 0); \
      acc[t_ * 4 + 2] = __builtin_amdgcn_mfma_f32_16x16x32_bf16(F[t_], b2_, acc[t_ * 4 + 2], 0, 0, 0); \
      acc[t_ * 4 + 3] = __builtin_amdgcn_mfma_f32_16x16x32_bf16(F[t_], b3_, acc[t_ * 4 + 3], 0, 0, 0); \
    }                                                                           \
  } while (0)

#define G2_HALF(F, W, PF, PFB) do {                                             \
    if (PF) frag_issue(baseW, (((W) + 3 + phase) & 15) * 32, PFB);              \
    const int k0_ = (((W) + phase) & 15) * 32;                                  \
    const bf16x8 a0_ = ld_frag(&hS[(l15     ) * 520 + k0_ + quad * 8]);         \
    const bf16x8 a1_ = ld_frag(&hS[(16 + l15) * 520 + k0_ + quad * 8]);         \
    const bf16x8 a2_ = ld_frag(&hS[(32 + l15) * 520 + k0_ + quad * 8]);         \
    const bf16x8 a3_ = ld_frag(&hS[(48 + l15) * 520 + k0_ + quad * 8]);         \
    _Pragma("unroll")                                                           \
    for (int e_ = 0; e_ < 4; e_++) {                                            \
      acc[0 * 4 + e_] = __builtin_amdgcn_mfma_f32_16x16x32_bf16(a0_, F[e_], acc[0 * 4 + e_], 0, 0, 0); \
      acc[1 * 4 + e_] = __builtin_amdgcn_mfma_f32_16x16x32_bf16(a1_, F[e_], acc[1 * 4 + e_], 0, 0, 0); \
      acc[2 * 4 + e_] = __builtin_amdgcn_mfma_f32_16x16x32_bf16(a2_, F[e_], acc[2 * 4 + e_], 0, 0, 0); \
      acc[3 * 4 + e_] = __builtin_amdgcn_mfma_f32_16x16x32_bf16(a3_, F[e_], acc[3 * 4 + e_], 0, 0, 0); \
    }                                                                           \
  } while (0)

// ---------------- prep: transpose + fp32->bf16 convert of Wh, Wc; init work queue ----------------
__global__ __launch_bounds__(256) void prep_w(
    const float* __restrict__ Wh, const float* __restrict__ Wc,
    unsigned short* __restrict__ WhT, unsigned short* __restrict__ WcT,
    int* __restrict__ q)
{
  if (blockIdx.x == 0 && blockIdx.y == 0 && threadIdx.x == 0) *q = 0;
  const float* src = blockIdx.y ? Wc : Wh;
  unsigned short* dst = blockIdx.y ? WcT : WhT;
  const int tr = (blockIdx.x >> 3) * 64;
  const int tc = (blockIdx.x & 7) * 64;
  const int tid = threadIdx.x;
  __shared__ float tile[64][65];
  for (int i = tid; i < 64 * 16; i += 256) {
    const int r = i >> 4, c4 = (i & 15) << 2;
    const float4 v = *(const float4*)(src + (size_t)(tr + r) * 512 + tc + c4);
    tile[r][c4 + 0] = v.x; tile[r][c4 + 1] = v.y;
    tile[r][c4 + 2] = v.z; tile[r][c4 + 3] = v.w;
  }
  __syncthreads();
  for (int i = tid; i < 64 * 16; i += 256) {
    const int r = i >> 4, c4 = (i & 15) << 2;
    ushort4 pk;
    pk.x = f2bf(tile[c4 + 0][r]); pk.y = f2bf(tile[c4 + 1][r]);
    pk.z = f2bf(tile[c4 + 2][r]); pk.w = f2bf(tile[c4 + 3][r]);
    *(ushort4*)(dst + (size_t)(tc + r) * 512 + tr + c4) = pk;
  }
}

// ---------------- main: 512-thread persistent blocks; 64 enc rows per pass ----------------
// 64 rows/pass halves the per-row weight L2 traffic and barrier count, and gives
// 16 MFMA (~80 cyc) per half-step. Weight frags are loaded global->reg with a
// 4-buffer rotation at prefetch distance 3 (~240 cyc/wave of cover, x2 waves/SIMD)
// so the MFMA's counted-vmcnt wait is satisfied by the time it issues.
__global__ __launch_bounds__(512, 2) void attn_main(
    const float* __restrict__ enc, const int* __restrict__ lens,
    const unsigned short* __restrict__ WhT, const float* __restrict__ bh,
    const unsigned short* __restrict__ WcT,
    float* __restrict__ pm, float* __restrict__ ps, float* __restrict__ po,
    int* __restrict__ q, int C, int Lc)
{
  const int tid  = threadIdx.x;
  const int wave = tid >> 6;       // 0..7
  const int lane = tid & 63;
  const int quad = lane >> 4;
  const int l15  = lane & 15;
  const int wbase = wave * 64;     // wave's 64-wide h-slab (GEMM1) / e-slab (GEMM2)

  __shared__ __align__(16) unsigned short encA[64 * 520];  // 66.6 KB
  __shared__ __align__(16) unsigned short hS[64 * 520];    // 66.6 KB
  __shared__ __align__(16) float bhS[512];
  __shared__ int itemS;

  bhS[tid] = bh[tid];
  const int nitems = 32 * C;

#pragma unroll 1
  for (;;) {
    __syncthreads();                       // protect itemS + LDS from previous item
    if (tid == 0) itemS = atomicAdd(q, 1);
    __syncthreads();
    const int item = itemS;
    if (item >= nitems) break;            // uniform across block
    const int b = item & 31;
    const int c = item >> 5;
    const int n = lens[b];
    const int l0 = c * Lc;
    const int nvalid = min(n - l0, Lc);
    if (nvalid <= 0) continue;

    const int phase = (item + wave) & 15;  // k-window de-phasing across waves/items

    float stM[4], stS[4], stO[4];
#pragma unroll
    for (int et = 0; et < 4; et++) { stM[et] = -1e30f; stS[et] = 0.f; stO[et] = 0.f; }

    f32x4 acc[16];  // shared by GEMM1 (acc[t*4+mt]) and GEMM2 (acc[mt*4+et])

#pragma unroll 1
    for (int r0 = 0; r0 < nvalid; r0 += 64) {
      // ---- stage 64 enc rows -> bf16 LDS (one copy shared by 8 waves) ----
      const float* encRow = enc + ((size_t)b * LL + l0 + r0) * EE;
      for (int i = tid; i < 64 * 128; i += 512) {
        const int m = i >> 7, e4 = (i & 127) << 2;
        const float4 v = *(const float4*)(encRow + (size_t)m * EE + e4);
        ushort4 pk;
        pk.x = f2bf(v.x); pk.y = f2bf(v.y); pk.z = f2bf(v.z); pk.w = f2bf(v.w);
        *(ushort4*)&encA[m * 520 + e4] = pk;
      }
      __syncthreads();

      // ================= GEMM1: hT[64 x 64] per wave = WhT-slab @ encT =================
#pragma unroll
      for (int i = 0; i < 16; i++) acc[i] = (f32x4){0.f, 0.f, 0.f, 0.f};
      {
        const unsigned short* baseW = WhT + (size_t)(wbase + l15) * 512 + quad * 8;
        bf16x8 f0[4], f1[4], f2[4], f3[4];
        frag_issue(baseW, ((0 + phase) & 15) * 32, f0);
        frag_issue(baseW, ((1 + phase) & 15) * 32, f1);
        frag_issue(baseW, ((2 + phase) & 15) * 32, f2);
#pragma unroll 1
        for (int i = 0; i < 4; i++) {
          const int w = i * 4;
          const bool pf = (i < 3);
          G1_HALF(f0, w + 0, true, f3);
          G1_HALF(f1, w + 1, pf,   f0);
          G1_HALF(f2, w + 2, pf,   f1);
          G1_HALF(f3, w + 3, pf,   f2);
        }
      }

      // ---- bias + tanh, pack 4 consecutive h -> one 8B LDS write of h[m][h] ----
#pragma unroll
      for (int t = 0; t < 4; t++) {
        const f32x4 bv = *(const f32x4*)&bhS[wbase + t * 16 + quad * 4];
#pragma unroll
        for (int mt = 0; mt < 4; mt++) {
          ushort4 pk;
          pk.x = f2bf(tanh_fast(acc[t * 4 + mt][0] + bv[0]));
          pk.y = f2bf(tanh_fast(acc[t * 4 + mt][1] + bv[1]));
          pk.z = f2bf(tanh_fast(acc[t * 4 + mt][2] + bv[2]));
          pk.w = f2bf(tanh_fast(acc[t * 4 + mt][3] + bv[3]));
          *(ushort4*)&hS[(mt * 16 + l15) * 520 + wbase + t * 16 + quad * 4] = pk;
        }
      }
      __syncthreads();

      // ================= GEMM2: logits[64 x 64] per wave = h @ WcT-slab =================
#pragma unroll
      for (int i = 0; i < 16; i++) acc[i] = (f32x4){0.f, 0.f, 0.f, 0.f};
      {
        const unsigned short* baseW = WcT + (size_t)(wbase + l15) * 512 + quad * 8;
        bf16x8 f0[4], f1[4], f2[4], f3[4];
        frag_issue(baseW, ((0 + phase) & 15) * 32, f0);
        frag_issue(baseW, ((1 + phase) & 15) * 32, f1);
        frag_issue(baseW, ((2 + phase) & 15) * 32, f2);
#pragma unroll 1
        for (int i = 0; i < 4; i++) {
          const int w = i * 4;
          const bool pf = (i < 3);
          G2_HALF(f0, w + 0, true, f3);
          G2_HALF(f1, w + 1, pf,   f0);
          G2_HALF(f2, w + 2, pf,   f1);
          G2_HALF(f3, w + 3, pf,   f2);
        }
      }

      // ---- masked online softmax over the 64 time rows of this pass ----
#pragma unroll
      for (int et = 0; et < 4; et++) {
        const int e = wbase + et * 16 + l15;
        float lm = -1e30f;
#pragma unroll
        for (int mt = 0; mt < 4; mt++)
#pragma unroll
          for (int r = 0; r < 4; r++) {
            const float vv = (r0 + mt * 16 + quad * 4 + r) < nvalid ? acc[mt * 4 + et][r] : -1e30f;
            lm = fmaxf(lm, vv);
          }
        lm = fmaxf(lm, __shfl_xor(lm, 16));
        lm = fmaxf(lm, __shfl_xor(lm, 32));
        float ls = 0.f, lo = 0.f;
#pragma unroll
        for (int mt = 0; mt < 4; mt++)
#pragma unroll
          for (int r = 0; r < 4; r++) {
            const float vv = (r0 + mt * 16 + quad * 4 + r) < nvalid ? acc[mt * 4 + et][r] : -1e30f;
            const float p  = __expf(vv - lm);
            const float ev = bf2f(encA[(mt * 16 + quad * 4 + r) * 520 + e]);
            ls += p;
            lo += p * ev;
          }
        ls += __shfl_xor(ls, 16); ls += __shfl_xor(ls, 32);
        lo += __shfl_xor(lo, 16); lo += __shfl_xor(lo, 32);
        const float Mn = fmaxf(stM[et], lm);
        const float sc = __expf(stM[et] - Mn);
        const float st = __expf(lm - Mn);
        stS[et] = stS[et] * sc + ls * st;
        stO[et] = stO[et] * sc + lo * st;
        stM[et] = Mn;
      }
      __syncthreads();
    }

    if (quad == 0) {
      const size_t base = ((size_t)b * C + c) * EE;
#pragma unroll
      for (int et = 0; et < 4; et++) {
        const int e = wbase + et * 16 + l15;
        pm[base + e] = stM[et];
        ps[base + e] = stS[et];
        po[base + e] = stO[et];
      }
    }
  }
}

// ---------------- combine over chunks (parallelized: 8 e-slabs x 4 c-groups) ----------------
__global__ __launch_bounds__(256) void attn_combine(
    const float* __restrict__ pm, const float* __restrict__ ps,
    const float* __restrict__ po, const int* __restrict__ lens,
    float* __restrict__ out, int C, int Lc)
{
  const int b  = blockIdx.y;
  const int e  = blockIdx.x * 64 + (threadIdx.x & 63);
  const int g  = threadIdx.x >> 6;  // c-group 0..3
  const int n  = lens[b];
  const int cmax = min(C, (n + Lc - 1) / Lc);

  float M = -1e30f, S = 0.f, O = 0.f;
  for (int c = g; c < cmax; c += 4) {
    const size_t base = ((size_t)b * C + c) * EE;
    const float m = pm[base + e];
    const float s = ps[base + e];
    const float o = po[base + e];
    const float Mn  = fmaxf(M, m);
    const float sc0 = __expf(M - Mn);
    const float sc1 = __expf(m - Mn);
    S = S * sc0 + s * sc1;
    O = O * sc0 + o * sc1;
    M = Mn;
  }

  __shared__ float sM[4][64], sS[4][64], sO[4][64];
  sM[g][threadIdx.x & 63] = M;
  sS[g][threadIdx.x & 63] = S;
  sO[g][threadIdx.x & 63] = O;
  __syncthreads();

  if (g == 0) {
    const int le = threadIdx.x & 63;
    float Mt = sM[0][le], St = sS[0][le], Ot = sO[0][le];
#pragma unroll
    for (int gg = 1; gg < 4; gg++) {
      const float m = sM[gg][le];
      const float Mn  = fmaxf(Mt, m);
      const float sc0 = __expf(Mt - Mn);
      const float sc1 = __expf(m - Mn);
      St = St * sc0 + sS[gg][le] * sc1;
      Ot = Ot * sc0 + sO[gg][le] * sc1;
      Mt = Mn;
    }
    out[(size_t)b * EE + e] = Ot / St;  // St > 0: c=0 always valid (lengths >= 1)
  }
}

extern "C" void kernel_launch(void* const* d_in, const int* in_sizes, int n_in,
                              void* d_out, int out_size, void* d_ws, size_t ws_size,
                              hipStream_t stream) {
  const float* enc  = (const float*)d_in[0];
  const int*   lens = (const int*)d_in[1];
  const float* Wh   = (const float*)d_in[2];
  const float* bh   = (const float*)d_in[3];
  const float* Wc   = (const float*)d_in[4];
  float* out = (float*)d_out;

  const size_t wbytes = (size_t)512 * 512 * sizeof(unsigned short);
  int C = 32;  // Lc=64 -> one 64-row pass per item
  while (C > 8 && ws_size < (size_t)3 * BB * C * EE * sizeof(float) + 2 * wbytes + 64)
    C >>= 1;
  const int Lc = LL / C;

  float* pm = (float*)d_ws;
  float* ps = pm + (size_t)BB * C * EE;
  float* po = ps + (size_t)BB * C * EE;
  unsigned short* WhT = (unsigned short*)(po + (size_t)BB * C * EE);
  unsigned short* WcT = WhT + (size_t)512 * 512;
  int* q = (int*)(WcT + (size_t)512 * 512);

  prep_w<<<dim3(64, 2), 256, 0, stream>>>(Wh, Wc, WhT, WcT, q);
  attn_main<<<dim3(256), 512, 0, stream>>>(enc, lens, WhT, bh, WcT, pm, ps, po, q, C, Lc);
  attn_combine<<<dim3(8, BB), 256, 0, stream>>>(pm, ps, po, lens, out, C, Lc);
}

// Round 5
// 308.469 us; speedup vs baseline: 1.1984x; 1.0162x over previous
//
#include <hip/hip_runtime.h>
#include <math.h>

#define BB 32
#define LL 2048
#define EE 512
#define HH 512

typedef __bf16 bf16_t;
typedef bf16_t bf16x8 __attribute__((ext_vector_type(8)));
typedef float f32x4 __attribute__((ext_vector_type(4)));
typedef unsigned short u16x8 __attribute__((ext_vector_type(8)));

__device__ __forceinline__ unsigned short f2bf(float f) {
  unsigned int u = __builtin_bit_cast(unsigned int, f);
  unsigned int r = (u + 0x7FFFu + ((u >> 16) & 1u)) >> 16;  // RNE
  return (unsigned short)r;
}
__device__ __forceinline__ float bf2f(unsigned short s) {
  unsigned int u = ((unsigned int)s) << 16;
  return __builtin_bit_cast(float, u);
}
__device__ __forceinline__ bf16x8 ld_frag(const unsigned short* p) {
  u16x8 raw = *(const u16x8*)p;
  return __builtin_bit_cast(bf16x8, raw);
}
__device__ __forceinline__ float tanh_fast(float x) {
  x = fminf(fmaxf(x, -15.f), 15.f);
  float e2 = __expf(2.f * x);
  return (e2 - 1.f) / (e2 + 1.f);
}

// load the 2 weight fragments of a 32-col x 32-k window, global->reg in MFMA layout.
// 32-col slabs (not 64) keep the accumulator at 32 regs so the whole wave fits in
// the 128-reg tier -> 4 waves/SIMD.
__device__ __forceinline__ void frag_issue2(const unsigned short* __restrict__ g,
                                            int k0, bf16x8 f[2]) {
#pragma unroll
  for (int i = 0; i < 2; i++) f[i] = ld_frag(g + (size_t)i * 16 * 512 + k0);
}

// one GEMM1 half-step: 8 MFMAs on window W from buffer F, then distance-2 prefetch
// of window W+2 back into F. All frag indices compile-time (no scratch).
#define G1_HALF(F, W, PF) do {                                                  \
    const int k0_ = (((W) + phase) & 15) * 32;                                  \
    const bf16x8 b0_ = ld_frag(&encA[(l15     ) * 520 + k0_ + quad * 8]);       \
    const bf16x8 b1_ = ld_frag(&encA[(16 + l15) * 520 + k0_ + quad * 8]);       \
    const bf16x8 b2_ = ld_frag(&encA[(32 + l15) * 520 + k0_ + quad * 8]);       \
    const bf16x8 b3_ = ld_frag(&encA[(48 + l15) * 520 + k0_ + quad * 8]);       \
    _Pragma("unroll")                                                           \
    for (int t_ = 0; t_ < 2; t_++) {                                            \
      acc[t_ * 4 + 0] = __builtin_amdgcn_mfma_f32_16x16x32_bf16(F[t_], b0_, acc[t_ * 4 + 0], 0, 0, 0); \
      acc[t_ * 4 + 1] = __builtin_amdgcn_mfma_f32_16x16x32_bf16(F[t_], b1_, acc[t_ * 4 + 1], 0, 0, 0); \
      acc[t_ * 4 + 2] = __builtin_amdgcn_mfma_f32_16x16x32_bf16(F[t_], b2_, acc[t_ * 4 + 2], 0, 0, 0); \
      acc[t_ * 4 + 3] = __builtin_amdgcn_mfma_f32_16x16x32_bf16(F[t_], b3_, acc[t_ * 4 + 3], 0, 0, 0); \
    }                                                                           \
    if (PF) frag_issue2(baseW, (((W) + 2 + phase) & 15) * 32, F);               \
  } while (0)

#define G2_HALF(F, W, PF) do {                                                  \
    const int k0_ = (((W) + phase) & 15) * 32;                                  \
    const bf16x8 a0_ = ld_frag(&hS[(l15     ) * 520 + k0_ + quad * 8]);         \
    const bf16x8 a1_ = ld_frag(&hS[(16 + l15) * 520 + k0_ + quad * 8]);         \
    const bf16x8 a2_ = ld_frag(&hS[(32 + l15) * 520 + k0_ + quad * 8]);         \
    const bf16x8 a3_ = ld_frag(&hS[(48 + l15) * 520 + k0_ + quad * 8]);         \
    _Pragma("unroll")                                                           \
    for (int e_ = 0; e_ < 2; e_++) {                                            \
      acc[0 * 2 + e_] = __builtin_amdgcn_mfma_f32_16x16x32_bf16(a0_, F[e_], acc[0 * 2 + e_], 0, 0, 0); \
      acc[2 + 2 * 1 * e_ + 0] = acc[2 + 2 * 1 * e_ + 0];                        \
      acc[1 * 2 + e_] = __builtin_amdgcn_mfma_f32_16x16x32_bf16(a1_, F[e_], acc[1 * 2 + e_], 0, 0, 0); \
      acc[2 * 2 + e_] = __builtin_amdgcn_mfma_f32_16x16x32_bf16(a2_, F[e_], acc[2 * 2 + e_], 0, 0, 0); \
      acc[3 * 2 + e_] = __builtin_amdgcn_mfma_f32_16x16x32_bf16(a3_, F[e_], acc[3 * 2 + e_], 0, 0, 0); \
    }                                                                           \
    if (PF) frag_issue2(baseW, (((W) + 2 + phase) & 15) * 32, F);               \
  } while (0)

// ---------------- prep: transpose + fp32->bf16 convert of Wh, Wc; init work queue ----------------
__global__ __launch_bounds__(256) void prep_w(
    const float* __restrict__ Wh, const float* __restrict__ Wc,
    unsigned short* __restrict__ WhT, unsigned short* __restrict__ WcT,
    int* __restrict__ q)
{
  if (blockIdx.x == 0 && blockIdx.y == 0 && threadIdx.x == 0) *q = 0;
  const float* src = blockIdx.y ? Wc : Wh;
  unsigned short* dst = blockIdx.y ? WcT : WhT;
  const int tr = (blockIdx.x >> 3) * 64;
  const int tc = (blockIdx.x & 7) * 64;
  const int tid = threadIdx.x;
  __shared__ float tile[64][65];
  for (int i = tid; i < 64 * 16; i += 256) {
    const int r = i >> 4, c4 = (i & 15) << 2;
    const float4 v = *(const float4*)(src + (size_t)(tr + r) * 512 + tc + c4);
    tile[r][c4 + 0] = v.x; tile[r][c4 + 1] = v.y;
    tile[r][c4 + 2] = v.z; tile[r][c4 + 3] = v.w;
  }
  __syncthreads();
  for (int i = tid; i < 64 * 16; i += 256) {
    const int r = i >> 4, c4 = (i & 15) << 2;
    ushort4 pk;
    pk.x = f2bf(tile[c4 + 0][r]); pk.y = f2bf(tile[c4 + 1][r]);
    pk.z = f2bf(tile[c4 + 2][r]); pk.w = f2bf(tile[c4 + 3][r]);
    *(ushort4*)(dst + (size_t)(tc + r) * 512 + tr + c4) = pk;
  }
}

// ---------------- main: 1024-thread persistent blocks; 16 waves x 32-col slabs; 64 rows/pass ----------------
// Why this shape: occupancy tiers are power-of-2 (<=128 regs -> 4 waves/SIMD). A
// 64-row pass with 32-col wave slabs needs only acc[8] (32 regs) + 2-frag weight
// dbuf (16 regs) -> fits 128 regs. 16 waves cover all 512 cols with ONE encA/hS
// copy (133 KB LDS, 1 block/CU), giving 4 waves/SIMD (2x R4) to hide the k-loop's
// L2 latency and the stage's HBM latency. Weight bytes/row and MFMA count match R4.
__global__ __launch_bounds__(1024, 4) void attn_main(
    const float* __restrict__ enc, const int* __restrict__ lens,
    const unsigned short* __restrict__ WhT, const float* __restrict__ bh,
    const unsigned short* __restrict__ WcT,
    float* __restrict__ pm, float* __restrict__ ps, float* __restrict__ po,
    int* __restrict__ q, int C, int Lc)
{
  const int tid  = threadIdx.x;
  const int lane = tid & 63;
  const int wave = tid >> 6;       // 0..15
  const int quad = lane >> 4;
  const int l15  = lane & 15;
  const int wbase = wave * 32;     // wave's 32-wide h-slab (GEMM1) / e-slab (GEMM2)

  __shared__ __align__(16) unsigned short encA[64 * 520];  // 66.6 KB
  __shared__ __align__(16) unsigned short hS[64 * 520];    // 66.6 KB
  __shared__ __align__(16) float bhS[512];
  __shared__ int itemS;

  if (tid < 512) bhS[tid] = bh[tid];
  const int nitems = 32 * C;

#pragma unroll 1
  for (;;) {
    __syncthreads();                       // protect itemS + LDS from previous item
    if (tid == 0) itemS = atomicAdd(q, 1);
    __syncthreads();
    const int item = itemS;
    if (item >= nitems) break;            // uniform across block
    const int b = item & 31;
    const int c = item >> 5;
    const int n = lens[b];
    const int l0 = c * Lc;
    const int nvalid = min(n - l0, Lc);
    if (nvalid <= 0) continue;

    const int phase = (item + wave) & 15;  // k-window de-phasing across waves/items

    float stM[2], stS[2], stO[2];
#pragma unroll
    for (int et = 0; et < 2; et++) { stM[et] = -1e30f; stS[et] = 0.f; stO[et] = 0.f; }

    f32x4 acc[8];  // GEMM1: acc[t*4+mt]; GEMM2: acc[mt*2+et] (live ranges disjoint)

#pragma unroll 1
    for (int r0 = 0; r0 < nvalid; r0 += 64) {
      // ---- stage 64 enc rows -> bf16 LDS (one copy shared by 16 waves) ----
      const float* encRow = enc + ((size_t)b * LL + l0 + r0) * EE;
      for (int i = tid; i < 64 * 128; i += 1024) {
        const int m = i >> 7, e4 = (i & 127) << 2;
        const float4 v = *(const float4*)(encRow + (size_t)m * EE + e4);
        ushort4 pk;
        pk.x = f2bf(v.x); pk.y = f2bf(v.y); pk.z = f2bf(v.z); pk.w = f2bf(v.w);
        *(ushort4*)&encA[m * 520 + e4] = pk;
      }
      __syncthreads();

      // ================= GEMM1: hT[32 x 64] per wave = WhT-slab @ encT =================
#pragma unroll
      for (int i = 0; i < 8; i++) acc[i] = (f32x4){0.f, 0.f, 0.f, 0.f};
      {
        const unsigned short* baseW = WhT + (size_t)(wbase + l15) * 512 + quad * 8;
        bf16x8 fA[2], fB[2];
        frag_issue2(baseW, ((0 + phase) & 15) * 32, fA);
        frag_issue2(baseW, ((1 + phase) & 15) * 32, fB);
#pragma unroll 1
        for (int kk = 0; kk < 16; kk += 2) {
          G1_HALF(fA, kk + 0, (kk + 2 < 16));
          G1_HALF(fB, kk + 1, (kk + 3 < 16));
        }
      }

      // ---- bias + tanh, pack 4 consecutive h -> one 8B LDS write of h[m][h] ----
#pragma unroll
      for (int t = 0; t < 2; t++) {
        const f32x4 bv = *(const f32x4*)&bhS[wbase + t * 16 + quad * 4];
#pragma unroll
        for (int mt = 0; mt < 4; mt++) {
          ushort4 pk;
          pk.x = f2bf(tanh_fast(acc[t * 4 + mt][0] + bv[0]));
          pk.y = f2bf(tanh_fast(acc[t * 4 + mt][1] + bv[1]));
          pk.z = f2bf(tanh_fast(acc[t * 4 + mt][2] + bv[2]));
          pk.w = f2bf(tanh_fast(acc[t * 4 + mt][3] + bv[3]));
          *(ushort4*)&hS[(mt * 16 + l15) * 520 + wbase + t * 16 + quad * 4] = pk;
        }
      }
      __syncthreads();

      // ================= GEMM2: logits[64 x 32] per wave = h @ WcT-slab =================
#pragma unroll
      for (int i = 0; i < 8; i++) acc[i] = (f32x4){0.f, 0.f, 0.f, 0.f};
      {
        const unsigned short* baseW = WcT + (size_t)(wbase + l15) * 512 + quad * 8;
        bf16x8 fA[2], fB[2];
        frag_issue2(baseW, ((0 + phase) & 15) * 32, fA);
        frag_issue2(baseW, ((1 + phase) & 15) * 32, fB);
#pragma unroll 1
        for (int kk = 0; kk < 16; kk += 2) {
          G2_HALF(fA, kk + 0, (kk + 2 < 16));
          G2_HALF(fB, kk + 1, (kk + 3 < 16));
        }
      }

      // ---- masked online softmax over the 64 time rows of this pass ----
#pragma unroll
      for (int et = 0; et < 2; et++) {
        const int e = wbase + et * 16 + l15;
        float lm = -1e30f;
#pragma unroll
        for (int mt = 0; mt < 4; mt++)
#pragma unroll
          for (int r = 0; r < 4; r++) {
            const float vv = (r0 + mt * 16 + quad * 4 + r) < nvalid ? acc[mt * 2 + et][r] : -1e30f;
            lm = fmaxf(lm, vv);
          }
        lm = fmaxf(lm, __shfl_xor(lm, 16));
        lm = fmaxf(lm, __shfl_xor(lm, 32));
        float ls = 0.f, lo = 0.f;
#pragma unroll
        for (int mt = 0; mt < 4; mt++)
#pragma unroll
          for (int r = 0; r < 4; r++) {
            const float vv = (r0 + mt * 16 + quad * 4 + r) < nvalid ? acc[mt * 2 + et][r] : -1e30f;
            const float p  = __expf(vv - lm);
            const float ev = bf2f(encA[(mt * 16 + quad * 4 + r) * 520 + e]);
            ls += p;
            lo += p * ev;
          }
        ls += __shfl_xor(ls, 16); ls += __shfl_xor(ls, 32);
        lo += __shfl_xor(lo, 16); lo += __shfl_xor(lo, 32);
        const float Mn = fmaxf(stM[et], lm);
        const float sc = __expf(stM[et] - Mn);
        const float st = __expf(lm - Mn);
        stS[et] = stS[et] * sc + ls * st;
        stO[et] = stO[et] * sc + lo * st;
        stM[et] = Mn;
      }
      __syncthreads();
    }

    if (quad == 0) {
      const size_t base = ((size_t)b * C + c) * EE;
#pragma unroll
      for (int et = 0; et < 2; et++) {
        const int e = wbase + et * 16 + l15;
        pm[base + e] = stM[et];
        ps[base + e] = stS[et];
        po[base + e] = stO[et];
      }
    }
  }
}

// ---------------- combine over chunks (parallelized: 8 e-slabs x 4 c-groups) ----------------
__global__ __launch_bounds__(256) void attn_combine(
    const float* __restrict__ pm, const float* __restrict__ ps,
    const float* __restrict__ po, const int* __restrict__ lens,
    float* __restrict__ out, int C, int Lc)
{
  const int b  = blockIdx.y;
  const int e  = blockIdx.x * 64 + (threadIdx.x & 63);
  const int g  = threadIdx.x >> 6;  // c-group 0..3
  const int n  = lens[b];
  const int cmax = min(C, (n + Lc - 1) / Lc);

  float M = -1e30f, S = 0.f, O = 0.f;
  for (int c = g; c < cmax; c += 4) {
    const size_t base = ((size_t)b * C + c) * EE;
    const float m = pm[base + e];
    const float s = ps[base + e];
    const float o = po[base + e];
    const float Mn  = fmaxf(M, m);
    const float sc0 = __expf(M - Mn);
    const float sc1 = __expf(m - Mn);
    S = S * sc0 + s * sc1;
    O = O * sc0 + o * sc1;
    M = Mn;
  }

  __shared__ float sM[4][64], sS[4][64], sO[4][64];
  sM[g][threadIdx.x & 63] = M;
  sS[g][threadIdx.x & 63] = S;
  sO[g][threadIdx.x & 63] = O;
  __syncthreads();

  if (g == 0) {
    const int le = threadIdx.x & 63;
    float Mt = sM[0][le], St = sS[0][le], Ot = sO[0][le];
#pragma unroll
    for (int gg = 1; gg < 4; gg++) {
      const float m = sM[gg][le];
      const float Mn  = fmaxf(Mt, m);
      const float sc0 = __expf(Mt - Mn);
      const float sc1 = __expf(m - Mn);
      St = St * sc0 + sS[gg][le] * sc1;
      Ot = Ot * sc0 + sO[gg][le] * sc1;
      Mt = Mn;
    }
    out[(size_t)b * EE + e] = Ot / St;  // St > 0: c=0 always valid (lengths >= 1)
  }
}

extern "C" void kernel_launch(void* const* d_in, const int* in_sizes, int n_in,
                              void* d_out, int out_size, void* d_ws, size_t ws_size,
                              hipStream_t stream) {
  const float* enc  = (const float*)d_in[0];
  const int*   lens = (const int*)d_in[1];
  const float* Wh   = (const float*)d_in[2];
  const float* bh   = (const float*)d_in[3];
  const float* Wc   = (const float*)d_in[4];
  float* out = (float*)d_out;

  const size_t wbytes = (size_t)512 * 512 * sizeof(unsigned short);
  int C = 32;  // Lc=64 -> one 64-row pass per item
  while (C > 8 && ws_size < (size_t)3 * BB * C * EE * sizeof(float) + 2 * wbytes + 64)
    C >>= 1;
  const int Lc = LL / C;

  float* pm = (float*)d_ws;
  float* ps = pm + (size_t)BB * C * EE;
  float* po = ps + (size_t)BB * C * EE;
  unsigned short* WhT = (unsigned short*)(po + (size_t)BB * C * EE);
  unsigned short* WcT = WhT + (size_t)512 * 512;
  int* q = (int*)(WcT + (size_t)512 * 512);

  prep_w<<<dim3(64, 2), 256, 0, stream>>>(Wh, Wc, WhT, WcT, q);
  attn_main<<<dim3(256), 1024, 0, stream>>>(enc, lens, WhT, bh, WcT, pm, ps, po, q, C, Lc);
  attn_combine<<<dim3(8, BB), 256, 0, stream>>>(pm, ps, po, lens, out, C, Lc);
}

// Round 6
// 307.284 us; speedup vs baseline: 1.2030x; 1.0039x over previous
//
#include <hip/hip_runtime.h>
#include <math.h>

#define BB 32
#define LL 2048
#define EE 512
#define HH 512

typedef __bf16 bf16_t;
typedef bf16_t bf16x8 __attribute__((ext_vector_type(8)));
typedef float f32x4 __attribute__((ext_vector_type(4)));
typedef unsigned short u16x8 __attribute__((ext_vector_type(8)));

__device__ __forceinline__ unsigned short f2bf(float f) {
  unsigned int u = __builtin_bit_cast(unsigned int, f);
  unsigned int r = (u + 0x7FFFu + ((u >> 16) & 1u)) >> 16;  // RNE
  return (unsigned short)r;
}
__device__ __forceinline__ float bf2f(unsigned short s) {
  unsigned int u = ((unsigned int)s) << 16;
  return __builtin_bit_cast(float, u);
}
__device__ __forceinline__ bf16x8 ld_frag(const unsigned short* p) {
  u16x8 raw = *(const u16x8*)p;
  return __builtin_bit_cast(bf16x8, raw);
}
__device__ __forceinline__ float tanh_fast(float x) {
  x = fminf(fmaxf(x, -15.f), 15.f);
  float e2 = __expf(2.f * x);
  return (e2 - 1.f) / (e2 + 1.f);
}

// load the 2 weight fragments of a 32-col x 32-k window, global->reg in MFMA layout.
__device__ __forceinline__ void frag_issue2(const unsigned short* __restrict__ g,
                                            int k0, bf16x8 f[2]) {
#pragma unroll
  for (int i = 0; i < 2; i++) f[i] = ld_frag(g + (size_t)i * 16 * 512 + k0);
}

// one GEMM1 half-step: 8 MFMAs on window W from buffer F, then distance-2 prefetch
// of window W+2 back into F. All frag indices compile-time (no scratch).
#define G1_HALF(F, W, PF) do {                                                  \
    const int k0_ = (((W) + phase) & 15) * 32;                                  \
    const bf16x8 b0_ = ld_frag(&encA[(l15     ) * 520 + k0_ + quad * 8]);       \
    const bf16x8 b1_ = ld_frag(&encA[(16 + l15) * 520 + k0_ + quad * 8]);       \
    const bf16x8 b2_ = ld_frag(&encA[(32 + l15) * 520 + k0_ + quad * 8]);       \
    const bf16x8 b3_ = ld_frag(&encA[(48 + l15) * 520 + k0_ + quad * 8]);       \
    _Pragma("unroll")                                                           \
    for (int t_ = 0; t_ < 2; t_++) {                                            \
      acc[t_ * 4 + 0] = __builtin_amdgcn_mfma_f32_16x16x32_bf16(F[t_], b0_, acc[t_ * 4 + 0], 0, 0, 0); \
      acc[t_ * 4 + 1] = __builtin_amdgcn_mfma_f32_16x16x32_bf16(F[t_], b1_, acc[t_ * 4 + 1], 0, 0, 0); \
      acc[t_ * 4 + 2] = __builtin_amdgcn_mfma_f32_16x16x32_bf16(F[t_], b2_, acc[t_ * 4 + 2], 0, 0, 0); \
      acc[t_ * 4 + 3] = __builtin_amdgcn_mfma_f32_16x16x32_bf16(F[t_], b3_, acc[t_ * 4 + 3], 0, 0, 0); \
    }                                                                           \
    if (PF) frag_issue2(baseW, (((W) + 2 + phase) & 15) * 32, F);               \
  } while (0)

#define G2_HALF(F, W, PF) do {                                                  \
    const int k0_ = (((W) + phase) & 15) * 32;                                  \
    const bf16x8 a0_ = ld_frag(&hS[(l15     ) * 520 + k0_ + quad * 8]);         \
    const bf16x8 a1_ = ld_frag(&hS[(16 + l15) * 520 + k0_ + quad * 8]);         \
    const bf16x8 a2_ = ld_frag(&hS[(32 + l15) * 520 + k0_ + quad * 8]);         \
    const bf16x8 a3_ = ld_frag(&hS[(48 + l15) * 520 + k0_ + quad * 8]);         \
    _Pragma("unroll")                                                           \
    for (int e_ = 0; e_ < 2; e_++) {                                            \
      acc[0 * 2 + e_] = __builtin_amdgcn_mfma_f32_16x16x32_bf16(a0_, F[e_], acc[0 * 2 + e_], 0, 0, 0); \
      acc[1 * 2 + e_] = __builtin_amdgcn_mfma_f32_16x16x32_bf16(a1_, F[e_], acc[1 * 2 + e_], 0, 0, 0); \
      acc[2 * 2 + e_] = __builtin_amdgcn_mfma_f32_16x16x32_bf16(a2_, F[e_], acc[2 * 2 + e_], 0, 0, 0); \
      acc[3 * 2 + e_] = __builtin_amdgcn_mfma_f32_16x16x32_bf16(a3_, F[e_], acc[3 * 2 + e_], 0, 0, 0); \
    }                                                                           \
    if (PF) frag_issue2(baseW, (((W) + 2 + phase) & 15) * 32, F);               \
  } while (0)

// ---------------- prep: transpose + fp32->bf16 convert of Wh, Wc; init work queue ----------------
__global__ __launch_bounds__(256) void prep_w(
    const float* __restrict__ Wh, const float* __restrict__ Wc,
    unsigned short* __restrict__ WhT, unsigned short* __restrict__ WcT,
    int* __restrict__ q)
{
  if (blockIdx.x == 0 && blockIdx.y == 0 && threadIdx.x == 0) *q = 0;
  const float* src = blockIdx.y ? Wc : Wh;
  unsigned short* dst = blockIdx.y ? WcT : WhT;
  const int tr = (blockIdx.x >> 3) * 64;
  const int tc = (blockIdx.x & 7) * 64;
  const int tid = threadIdx.x;
  __shared__ float tile[64][65];
  for (int i = tid; i < 64 * 16; i += 256) {
    const int r = i >> 4, c4 = (i & 15) << 2;
    const float4 v = *(const float4*)(src + (size_t)(tr + r) * 512 + tc + c4);
    tile[r][c4 + 0] = v.x; tile[r][c4 + 1] = v.y;
    tile[r][c4 + 2] = v.z; tile[r][c4 + 3] = v.w;
  }
  __syncthreads();
  for (int i = tid; i < 64 * 16; i += 256) {
    const int r = i >> 4, c4 = (i & 15) << 2;
    ushort4 pk;
    pk.x = f2bf(tile[c4 + 0][r]); pk.y = f2bf(tile[c4 + 1][r]);
    pk.z = f2bf(tile[c4 + 2][r]); pk.w = f2bf(tile[c4 + 3][r]);
    *(ushort4*)(dst + (size_t)(tc + r) * 512 + tr + c4) = pk;
  }
}

// ---------------- main: 1024-thread persistent blocks; 16 waves x 32-col slabs; 64 rows/pass ----------------
// __launch_bounds__(1024, 1): a 1024-thread block (16 waves) must fit 4 waves/SIMD,
// so the HW register cap is 128/wave regardless; min-blocks=1 lets the allocator
// actually USE the full 128 (R5's min=4 forced a 64-reg budget -> ~28 MB of scratch
// spill traffic round-tripping inside the k-loops; WRITE_SIZE 20.7 MB vs 6.3 ideal).
// Demand ~106 regs (acc 32 + frag dbuf 16 + softmax 6 + staging/addressing) -> fits.
__global__ __launch_bounds__(1024, 1) void attn_main(
    const float* __restrict__ enc, const int* __restrict__ lens,
    const unsigned short* __restrict__ WhT, const float* __restrict__ bh,
    const unsigned short* __restrict__ WcT,
    float* __restrict__ pm, float* __restrict__ ps, float* __restrict__ po,
    int* __restrict__ q, int C, int Lc)
{
  const int tid  = threadIdx.x;
  const int lane = tid & 63;
  const int wave = tid >> 6;       // 0..15
  const int quad = lane >> 4;
  const int l15  = lane & 15;
  const int wbase = wave * 32;     // wave's 32-wide h-slab (GEMM1) / e-slab (GEMM2)

  __shared__ __align__(16) unsigned short encA[64 * 520];  // 66.6 KB
  __shared__ __align__(16) unsigned short hS[64 * 520];    // 66.6 KB
  __shared__ __align__(16) float bhS[512];
  __shared__ int itemS;

  if (tid < 512) bhS[tid] = bh[tid];
  const int nitems = 32 * C;

#pragma unroll 1
  for (;;) {
    __syncthreads();                       // protect itemS + LDS from previous item
    if (tid == 0) itemS = atomicAdd(q, 1);
    __syncthreads();
    const int item = itemS;
    if (item >= nitems) break;            // uniform across block
    const int b = item & 31;
    const int c = item >> 5;
    const int n = lens[b];
    const int l0 = c * Lc;
    const int nvalid = min(n - l0, Lc);
    if (nvalid <= 0) continue;

    const int phase = (item + wave) & 15;  // k-window de-phasing across waves/items

    float stM[2], stS[2], stO[2];
#pragma unroll
    for (int et = 0; et < 2; et++) { stM[et] = -1e30f; stS[et] = 0.f; stO[et] = 0.f; }

    f32x4 acc[8];  // GEMM1: acc[t*4+mt]; GEMM2: acc[mt*2+et] (live ranges disjoint)

#pragma unroll 1
    for (int r0 = 0; r0 < nvalid; r0 += 64) {
      // ---- stage 64 enc rows -> bf16 LDS (one copy shared by 16 waves) ----
      const float* encRow = enc + ((size_t)b * LL + l0 + r0) * EE;
      for (int i = tid; i < 64 * 128; i += 1024) {
        const int m = i >> 7, e4 = (i & 127) << 2;
        const float4 v = *(const float4*)(encRow + (size_t)m * EE + e4);
        ushort4 pk;
        pk.x = f2bf(v.x); pk.y = f2bf(v.y); pk.z = f2bf(v.z); pk.w = f2bf(v.w);
        *(ushort4*)&encA[m * 520 + e4] = pk;
      }
      __syncthreads();

      // ================= GEMM1: hT[32 x 64] per wave = WhT-slab @ encT =================
#pragma unroll
      for (int i = 0; i < 8; i++) acc[i] = (f32x4){0.f, 0.f, 0.f, 0.f};
      {
        const unsigned short* baseW = WhT + (size_t)(wbase + l15) * 512 + quad * 8;
        bf16x8 fA[2], fB[2];
        frag_issue2(baseW, ((0 + phase) & 15) * 32, fA);
        frag_issue2(baseW, ((1 + phase) & 15) * 32, fB);
#pragma unroll 1
        for (int kk = 0; kk < 16; kk += 2) {
          G1_HALF(fA, kk + 0, (kk + 2 < 16));
          G1_HALF(fB, kk + 1, (kk + 3 < 16));
        }
      }

      // ---- bias + tanh, pack 4 consecutive h -> one 8B LDS write of h[m][h] ----
#pragma unroll
      for (int t = 0; t < 2; t++) {
        const f32x4 bv = *(const f32x4*)&bhS[wbase + t * 16 + quad * 4];
#pragma unroll
        for (int mt = 0; mt < 4; mt++) {
          ushort4 pk;
          pk.x = f2bf(tanh_fast(acc[t * 4 + mt][0] + bv[0]));
          pk.y = f2bf(tanh_fast(acc[t * 4 + mt][1] + bv[1]));
          pk.z = f2bf(tanh_fast(acc[t * 4 + mt][2] + bv[2]));
          pk.w = f2bf(tanh_fast(acc[t * 4 + mt][3] + bv[3]));
          *(ushort4*)&hS[(mt * 16 + l15) * 520 + wbase + t * 16 + quad * 4] = pk;
        }
      }
      __syncthreads();

      // ================= GEMM2: logits[64 x 32] per wave = h @ WcT-slab =================
#pragma unroll
      for (int i = 0; i < 8; i++) acc[i] = (f32x4){0.f, 0.f, 0.f, 0.f};
      {
        const unsigned short* baseW = WcT + (size_t)(wbase + l15) * 512 + quad * 8;
        bf16x8 fA[2], fB[2];
        frag_issue2(baseW, ((0 + phase) & 15) * 32, fA);
        frag_issue2(baseW, ((1 + phase) & 15) * 32, fB);
#pragma unroll 1
        for (int kk = 0; kk < 16; kk += 2) {
          G2_HALF(fA, kk + 0, (kk + 2 < 16));
          G2_HALF(fB, kk + 1, (kk + 3 < 16));
        }
      }

      // ---- masked online softmax over the 64 time rows of this pass ----
#pragma unroll
      for (int et = 0; et < 2; et++) {
        const int e = wbase + et * 16 + l15;
        float lm = -1e30f;
#pragma unroll
        for (int mt = 0; mt < 4; mt++)
#pragma unroll
          for (int r = 0; r < 4; r++) {
            const float vv = (r0 + mt * 16 + quad * 4 + r) < nvalid ? acc[mt * 2 + et][r] : -1e30f;
            lm = fmaxf(lm, vv);
          }
        lm = fmaxf(lm, __shfl_xor(lm, 16));
        lm = fmaxf(lm, __shfl_xor(lm, 32));
        float ls = 0.f, lo = 0.f;
#pragma unroll
        for (int mt = 0; mt < 4; mt++)
#pragma unroll
          for (int r = 0; r < 4; r++) {
            const float vv = (r0 + mt * 16 + quad * 4 + r) < nvalid ? acc[mt * 2 + et][r] : -1e30f;
            const float p  = __expf(vv - lm);
            const float ev = bf2f(encA[(mt * 16 + quad * 4 + r) * 520 + e]);
            ls += p;
            lo += p * ev;
          }
        ls += __shfl_xor(ls, 16); ls += __shfl_xor(ls, 32);
        lo += __shfl_xor(lo, 16); lo += __shfl_xor(lo, 32);
        const float Mn = fmaxf(stM[et], lm);
        const float sc = __expf(stM[et] - Mn);
        const float st = __expf(lm - Mn);
        stS[et] = stS[et] * sc + ls * st;
        stO[et] = stO[et] * sc + lo * st;
        stM[et] = Mn;
      }
      __syncthreads();
    }

    if (quad == 0) {
      const size_t base = ((size_t)b * C + c) * EE;
#pragma unroll
      for (int et = 0; et < 2; et++) {
        const int e = wbase + et * 16 + l15;
        pm[base + e] = stM[et];
        ps[base + e] = stS[et];
        po[base + e] = stO[et];
      }
    }
  }
}

// ---------------- combine over chunks (parallelized: 8 e-slabs x 4 c-groups) ----------------
__global__ __launch_bounds__(256) void attn_combine(
    const float* __restrict__ pm, const float* __restrict__ ps,
    const float* __restrict__ po, const int* __restrict__ lens,
    float* __restrict__ out, int C, int Lc)
{
  const int b  = blockIdx.y;
  const int e  = blockIdx.x * 64 + (threadIdx.x & 63);
  const int g  = threadIdx.x >> 6;  // c-group 0..3
  const int n  = lens[b];
  const int cmax = min(C, (n + Lc - 1) / Lc);

  float M = -1e30f, S = 0.f, O = 0.f;
  for (int c = g; c < cmax; c += 4) {
    const size_t base = ((size_t)b * C + c) * EE;
    const float m = pm[base + e];
    const float s = ps[base + e];
    const float o = po[base + e];
    const float Mn  = fmaxf(M, m);
    const float sc0 = __expf(M - Mn);
    const float sc1 = __expf(m - Mn);
    S = S * sc0 + s * sc1;
    O = O * sc0 + o * sc1;
    M = Mn;
  }

  __shared__ float sM[4][64], sS[4][64], sO[4][64];
  sM[g][threadIdx.x & 63] = M;
  sS[g][threadIdx.x & 63] = S;
  sO[g][threadIdx.x & 63] = O;
  __syncthreads();

  if (g == 0) {
    const int le = threadIdx.x & 63;
    float Mt = sM[0][le], St = sS[0][le], Ot = sO[0][le];
#pragma unroll
    for (int gg = 1; gg < 4; gg++) {
      const float m = sM[gg][le];
      const float Mn  = fmaxf(Mt, m);
      const float sc0 = __expf(Mt - Mn);
      const float sc1 = __expf(m - Mn);
      St = St * sc0 + sS[gg][le] * sc1;
      Ot = Ot * sc0 + sO[gg][le] * sc1;
      Mt = Mn;
    }
    out[(size_t)b * EE + e] = Ot / St;  // St > 0: c=0 always valid (lengths >= 1)
  }
}

extern "C" void kernel_launch(void* const* d_in, const int* in_sizes, int n_in,
                              void* d_out, int out_size, void* d_ws, size_t ws_size,
                              hipStream_t stream) {
  const float* enc  = (const float*)d_in[0];
  const int*   lens = (const int*)d_in[1];
  const float* Wh   = (const float*)d_in[2];
  const float* bh   = (const float*)d_in[3];
  const float* Wc   = (const float*)d_in[4];
  float* out = (float*)d_out;

  const size_t wbytes = (size_t)512 * 512 * sizeof(unsigned short);
  int C = 32;  // Lc=64 -> one 64-row pass per item
  while (C > 8 && ws_size < (size_t)3 * BB * C * EE * sizeof(float) + 2 * wbytes + 64)
    C >>= 1;
  const int Lc = LL / C;

  float* pm = (float*)d_ws;
  float* ps = pm + (size_t)BB * C * EE;
  float* po = ps + (size_t)BB * C * EE;
  unsigned short* WhT = (unsigned short*)(po + (size_t)BB * C * EE);
  unsigned short* WcT = WhT + (size_t)512 * 512;
  int* q = (int*)(WcT + (size_t)512 * 512);

  prep_w<<<dim3(64, 2), 256, 0, stream>>>(Wh, Wc, WhT, WcT, q);
  attn_main<<<dim3(256), 1024, 0, stream>>>(enc, lens, WhT, bh, WcT, pm, ps, po, q, C, Lc);
  attn_combine<<<dim3(8, BB), 256, 0, stream>>>(pm, ps, po, lens, out, C, Lc);
}

// Round 7
// 276.664 us; speedup vs baseline: 1.3362x; 1.1107x over previous
//
#include <hip/hip_runtime.h>
#include <math.h>

#define BB 32
#define LL 2048
#define EE 512
#define HH 512
#define WSL 32   // packed slab row stride (ushorts): 64B rows, lane-sequential writes,
                 // bank-uniform b128 frag reads (R0-proven weight path — keep verbatim)

typedef __bf16 bf16_t;
typedef bf16_t bf16x8 __attribute__((ext_vector_type(8)));
typedef float f32x4 __attribute__((ext_vector_type(4)));
typedef unsigned short u16x8 __attribute__((ext_vector_type(8)));

__device__ __forceinline__ unsigned short f2bf(float f) {
  unsigned int u = __builtin_bit_cast(unsigned int, f);
  unsigned int r = (u + 0x7FFFu + ((u >> 16) & 1u)) >> 16;  // RNE
  return (unsigned short)r;
}
__device__ __forceinline__ float bf2f(unsigned short s) {
  unsigned int u = ((unsigned int)s) << 16;
  return __builtin_bit_cast(float, u);
}
__device__ __forceinline__ bf16x8 ld_frag(const unsigned short* p) {
  u16x8 raw = *(const u16x8*)p;
  return __builtin_bit_cast(bf16x8, raw);
}
__device__ __forceinline__ float tanh_fast(float x) {
  x = fminf(fmaxf(x, -15.f), 15.f);
  float e2 = __expf(2.f * x);
  return (e2 - 1.f) / (e2 + 1.f);
}

// issue the 4 global 16B loads for one 64-row x 32-k weight slab (wave-private rows)
__device__ __forceinline__ void w_issue(const unsigned short* __restrict__ Wt,
                                        int rbase, int k0, int lane, u16x8 t[4]) {
  const unsigned short* g = Wt + (size_t)(rbase + (lane >> 2)) * 512 + k0 + (lane & 3) * 8;
#pragma unroll
  for (int i = 0; i < 4; i++) t[i] = *(const u16x8*)(g + i * 16 * 512);
}
// write the slab into this wave's LDS buffer: offset = lane*16B (perfectly sequential)
__device__ __forceinline__ void w_write(unsigned short* buf, int lane, const u16x8 t[4]) {
  unsigned short* d = buf + (lane >> 2) * WSL + (lane & 3) * 8;
#pragma unroll
  for (int i = 0; i < 4; i++) *(u16x8*)(d + i * 16 * WSL) = t[i];
}

// ---------------- prep: transpose + fp32->bf16 convert of Wh, Wc; init work queue ----------------
__global__ __launch_bounds__(256) void prep_w(
    const float* __restrict__ Wh, const float* __restrict__ Wc,
    unsigned short* __restrict__ WhT, unsigned short* __restrict__ WcT,
    int* __restrict__ q)
{
  if (blockIdx.x == 0 && blockIdx.y == 0 && threadIdx.x == 0) *q = 0;
  const float* src = blockIdx.y ? Wc : Wh;
  unsigned short* dst = blockIdx.y ? WcT : WhT;
  const int tr = (blockIdx.x >> 3) * 64;
  const int tc = (blockIdx.x & 7) * 64;
  const int tid = threadIdx.x;
  __shared__ float tile[64][65];
  for (int i = tid; i < 64 * 16; i += 256) {
    const int r = i >> 4, c4 = (i & 15) << 2;
    const float4 v = *(const float4*)(src + (size_t)(tr + r) * 512 + tc + c4);
    tile[r][c4 + 0] = v.x; tile[r][c4 + 1] = v.y;
    tile[r][c4 + 2] = v.z; tile[r][c4 + 3] = v.w;
  }
  __syncthreads();
  for (int i = tid; i < 64 * 16; i += 256) {
    const int r = i >> 4, c4 = (i & 15) << 2;
    ushort4 pk;
    pk.x = f2bf(tile[c4 + 0][r]); pk.y = f2bf(tile[c4 + 1][r]);
    pk.z = f2bf(tile[c4 + 2][r]); pk.w = f2bf(tile[c4 + 3][r]);
    *(ushort4*)(dst + (size_t)(tc + r) * 512 + tr + c4) = pk;
  }
}

// ---------------- main: R0 structure + cross-item async enc staging (T14) ----------------
// R0 (140us) is the proven base: 512 threads, LDS weight-slab pipeline (MFMA waits
// lgkm ~120cyc, globals 2 half-steps upstream), 1 pass (32 rows) per item at C=64.
// New: encA/hS are ping-pong buffers; the NEXT item's enc loads are issued after
// GEMM2 (newest in vmcnt FIFO -> no interference with the slab dance) and written
// to LDS at the next item's top -> the serial stage phase leaves the critical path.
__global__ __launch_bounds__(512, 2) void attn_main(
    const float* __restrict__ enc, const int* __restrict__ lens,
    const unsigned short* __restrict__ WhT, const float* __restrict__ bh,
    const unsigned short* __restrict__ WcT,
    float* __restrict__ pm, float* __restrict__ ps, float* __restrict__ po,
    int* __restrict__ q, int C, int Lc)
{
  const int tid  = threadIdx.x;
  const int wave = tid >> 6;       // 0..7
  const int lane = tid & 63;
  const int quad = lane >> 4;
  const int l15  = lane & 15;
  const int wbase = wave * 64;     // wave's 64-wide h-slab (GEMM1) / e-slab (GEMM2)

  __shared__ __align__(16) unsigned short ebuf[2][32 * 520];         // 66.6 KB (enc/h ping-pong)
  __shared__ __align__(16) unsigned short wslabS[8 * 2 * 64 * WSL];  // 64 KB
  __shared__ __align__(16) float bhS[512];
  __shared__ int itemS;

  unsigned short* sl0 = &wslabS[(wave * 2 + 0) * 64 * WSL];
  unsigned short* sl1 = &wslabS[(wave * 2 + 1) * 64 * WSL];

  bhS[tid] = bh[tid];
  const int nitems = 32 * C;

  // ---- prologue: pop first VALID item (tid0 skips empty chunks without barriers) ----
  if (tid == 0) {
    int it;
    for (;;) {
      it = atomicAdd(q, 1);
      if (it >= nitems || lens[it & 31] > (it >> 5) * Lc) break;
    }
    itemS = it;
  }
  __syncthreads();
  int item = itemS;
  int p = 0;

  float4 eR[8];  // next enc tile in flight (32 regs; dead during GEMM1/pack)
  if (item < nitems) {
    const float* src = enc + ((size_t)(item & 31) * LL + (size_t)(item >> 5) * Lc) * EE;
#pragma unroll
    for (int k = 0; k < 8; k++) {
      const int i = tid + k * 512;
      eR[k] = *(const float4*)(src + (size_t)(i >> 7) * EE + ((i & 127) << 2));
    }
  }

#pragma unroll 1
  for (;;) {
    if (item >= nitems) break;
    const int b = item & 31;
    const int c = item >> 5;
    const int l0 = c * Lc;
    const int nvalid = min(lens[b] - l0, Lc);   // >= 1 (pop skips invalid)
    const int phase = (item + wave) & 15;       // k-window de-phasing
    unsigned short* encA = ebuf[p];
    unsigned short* hS   = ebuf[p ^ 1];

    float stM[4], stS[4], stO[4];
#pragma unroll
    for (int et = 0; et < 4; et++) { stM[et] = -1e30f; stS[et] = 0.f; stO[et] = 0.f; }

    int nextItem = nitems;

#pragma unroll 1
    for (int r0 = 0; r0 < nvalid; r0 += 32) {
      const bool lastPass = (r0 + 32 >= nvalid);

      // ---- stage: pass 0 writes the PREFETCHED regs; later passes load synchronously ----
      if (r0 == 0) {
#pragma unroll
        for (int k = 0; k < 8; k++) {
          const int i = tid + k * 512;
          const float4 v = eR[k];
          ushort4 pk;
          pk.x = f2bf(v.x); pk.y = f2bf(v.y); pk.z = f2bf(v.z); pk.w = f2bf(v.w);
          *(ushort4*)&encA[(i >> 7) * 520 + ((i & 127) << 2)] = pk;
        }
      } else {
        const float* encRow = enc + ((size_t)b * LL + l0 + r0) * EE;
        for (int i = tid; i < 32 * 128; i += 512) {
          const int m = i >> 7, e4 = (i & 127) << 2;
          const float4 v = *(const float4*)(encRow + (size_t)m * EE + e4);
          ushort4 pk;
          pk.x = f2bf(v.x); pk.y = f2bf(v.y); pk.z = f2bf(v.z); pk.w = f2bf(v.w);
          *(ushort4*)&encA[m * 520 + e4] = pk;
        }
      }
      // pop next valid item while others stage; published by the barrier below
      if (lastPass && tid == 0) {
        int it;
        for (;;) {
          it = atomicAdd(q, 1);
          if (it >= nitems || lens[it & 31] > (it >> 5) * Lc) break;
        }
        itemS = it;
      }
      __syncthreads();

      // ================= GEMM1: hT[64 x 32] per wave = WhT @ encT (R0 slab dance) =================
      f32x4 acc1[4][2];
#pragma unroll
      for (int t = 0; t < 4; t++)
        for (int mt = 0; mt < 2; mt++) acc1[t][mt] = (f32x4){0.f, 0.f, 0.f, 0.f};
      {
        u16x8 tA[4], tB[4];
        w_issue(WhT, wbase, ((0 + phase) & 15) * 32, lane, tA);
        w_issue(WhT, wbase, ((1 + phase) & 15) * 32, lane, tB);
        w_write(sl0, lane, tA);           // waits only tA's loads; tB stays in flight
#pragma unroll 1
        for (int kk = 0; kk < 16; kk += 2) {
          w_write(sl1, lane, tB);
          if (kk + 2 < 16) w_issue(WhT, wbase, ((kk + 2 + phase) & 15) * 32, lane, tA);
          {
            const int k0 = ((kk + phase) & 15) * 32;
            const bf16x8 b0 = ld_frag(&encA[l15 * 520 + k0 + quad * 8]);
            const bf16x8 b1 = ld_frag(&encA[(16 + l15) * 520 + k0 + quad * 8]);
#pragma unroll
            for (int t = 0; t < 4; t++) {
              const bf16x8 af = ld_frag(&sl0[(t * 16 + l15) * WSL + quad * 8]);
              acc1[t][0] = __builtin_amdgcn_mfma_f32_16x16x32_bf16(af, b0, acc1[t][0], 0, 0, 0);
              acc1[t][1] = __builtin_amdgcn_mfma_f32_16x16x32_bf16(af, b1, acc1[t][1], 0, 0, 0);
            }
          }
          if (kk + 2 < 16) w_write(sl0, lane, tA);
          if (kk + 3 < 16) w_issue(WhT, wbase, ((kk + 3 + phase) & 15) * 32, lane, tB);
          {
            const int k0 = ((kk + 1 + phase) & 15) * 32;
            const bf16x8 b0 = ld_frag(&encA[l15 * 520 + k0 + quad * 8]);
            const bf16x8 b1 = ld_frag(&encA[(16 + l15) * 520 + k0 + quad * 8]);
#pragma unroll
            for (int t = 0; t < 4; t++) {
              const bf16x8 af = ld_frag(&sl1[(t * 16 + l15) * WSL + quad * 8]);
              acc1[t][0] = __builtin_amdgcn_mfma_f32_16x16x32_bf16(af, b0, acc1[t][0], 0, 0, 0);
              acc1[t][1] = __builtin_amdgcn_mfma_f32_16x16x32_bf16(af, b1, acc1[t][1], 0, 0, 0);
            }
          }
        }
      }

      // ---- bias + tanh, pack 4 consecutive h -> one 8B LDS write of h[m][h] ----
#pragma unroll
      for (int t = 0; t < 4; t++) {
        const f32x4 bv = *(const f32x4*)&bhS[wbase + t * 16 + quad * 4];
#pragma unroll
        for (int mt = 0; mt < 2; mt++) {
          ushort4 pk;
          pk.x = f2bf(tanh_fast(acc1[t][mt][0] + bv[0]));
          pk.y = f2bf(tanh_fast(acc1[t][mt][1] + bv[1]));
          pk.z = f2bf(tanh_fast(acc1[t][mt][2] + bv[2]));
          pk.w = f2bf(tanh_fast(acc1[t][mt][3] + bv[3]));
          *(ushort4*)&hS[(mt * 16 + l15) * 520 + wbase + t * 16 + quad * 4] = pk;
        }
      }
      __syncthreads();

      // ================= GEMM2: logits[32 x 64] per wave = h @ WcT-slab =================
      f32x4 acc2[2][4];
#pragma unroll
      for (int mt = 0; mt < 2; mt++)
        for (int et = 0; et < 4; et++) acc2[mt][et] = (f32x4){0.f, 0.f, 0.f, 0.f};
      {
        u16x8 tA[4], tB[4];
        w_issue(WcT, wbase, ((0 + phase) & 15) * 32, lane, tA);
        w_issue(WcT, wbase, ((1 + phase) & 15) * 32, lane, tB);
        w_write(sl0, lane, tA);
#pragma unroll 1
        for (int kk = 0; kk < 16; kk += 2) {
          w_write(sl1, lane, tB);
          if (kk + 2 < 16) w_issue(WcT, wbase, ((kk + 2 + phase) & 15) * 32, lane, tA);
          {
            const int k0 = ((kk + phase) & 15) * 32;
            const bf16x8 a0 = ld_frag(&hS[l15 * 520 + k0 + quad * 8]);
            const bf16x8 a1 = ld_frag(&hS[(16 + l15) * 520 + k0 + quad * 8]);
#pragma unroll
            for (int et = 0; et < 4; et++) {
              const bf16x8 bf = ld_frag(&sl0[(et * 16 + l15) * WSL + quad * 8]);
              acc2[0][et] = __builtin_amdgcn_mfma_f32_16x16x32_bf16(a0, bf, acc2[0][et], 0, 0, 0);
              acc2[1][et] = __builtin_amdgcn_mfma_f32_16x16x32_bf16(a1, bf, acc2[1][et], 0, 0, 0);
            }
          }
          if (kk + 2 < 16) w_write(sl0, lane, tA);
          if (kk + 3 < 16) w_issue(WcT, wbase, ((kk + 3 + phase) & 15) * 32, lane, tB);
          {
            const int k0 = ((kk + 1 + phase) & 15) * 32;
            const bf16x8 a0 = ld_frag(&hS[l15 * 520 + k0 + quad * 8]);
            const bf16x8 a1 = ld_frag(&hS[(16 + l15) * 520 + k0 + quad * 8]);
#pragma unroll
            for (int et = 0; et < 4; et++) {
              const bf16x8 bf = ld_frag(&sl1[(et * 16 + l15) * WSL + quad * 8]);
              acc2[0][et] = __builtin_amdgcn_mfma_f32_16x16x32_bf16(a0, bf, acc2[0][et], 0, 0, 0);
              acc2[1][et] = __builtin_amdgcn_mfma_f32_16x16x32_bf16(a1, bf, acc2[1][et], 0, 0, 0);
            }
          }
        }
      }

      // ---- issue NEXT item's enc loads (newest in vmcnt FIFO; latency hides under softmax) ----
      if (lastPass) {
        nextItem = itemS;
        if (nextItem < nitems) {
          const float* src = enc + ((size_t)(nextItem & 31) * LL + (size_t)(nextItem >> 5) * Lc) * EE;
#pragma unroll
          for (int k = 0; k < 8; k++) {
            const int i = tid + k * 512;
            eR[k] = *(const float4*)(src + (size_t)(i >> 7) * EE + ((i & 127) << 2));
          }
        }
      }

      // ---- masked online softmax over the 32 time rows of this pass ----
      bool ok[2][4];
#pragma unroll
      for (int mt = 0; mt < 2; mt++)
#pragma unroll
        for (int r = 0; r < 4; r++)
          ok[mt][r] = (r0 + mt * 16 + quad * 4 + r) < nvalid;

#pragma unroll
      for (int et = 0; et < 4; et++) {
        const int e = wbase + et * 16 + l15;
        float v[2][4];
        float lm = -1e30f;
#pragma unroll
        for (int mt = 0; mt < 2; mt++)
#pragma unroll
          for (int r = 0; r < 4; r++) {
            v[mt][r] = ok[mt][r] ? acc2[mt][et][r] : -1e30f;
            lm = fmaxf(lm, v[mt][r]);
          }
        lm = fmaxf(lm, __shfl_xor(lm, 16));
        lm = fmaxf(lm, __shfl_xor(lm, 32));
        float ls = 0.f, lo = 0.f;
#pragma unroll
        for (int mt = 0; mt < 2; mt++)
#pragma unroll
          for (int r = 0; r < 4; r++) {
            const float pexp = __expf(v[mt][r] - lm);
            const float ev = bf2f(encA[(mt * 16 + quad * 4 + r) * 520 + e]);
            ls += pexp;
            lo += pexp * ev;
          }
        ls += __shfl_xor(ls, 16); ls += __shfl_xor(ls, 32);
        lo += __shfl_xor(lo, 16); lo += __shfl_xor(lo, 32);
        const float Mn = fmaxf(stM[et], lm);
        const float sc = __expf(stM[et] - Mn);
        const float st = __expf(lm - Mn);
        stS[et] = stS[et] * sc + ls * st;
        stO[et] = stO[et] * sc + lo * st;
        stM[et] = Mn;
      }
      __syncthreads();   // end of pass: all reads of encA/hS complete
    }

    if (quad == 0) {
      const size_t base = ((size_t)b * C + c) * EE;
#pragma unroll
      for (int et = 0; et < 4; et++) {
        const int e = wbase + et * 16 + l15;
        pm[base + e] = stM[et];
        ps[base + e] = stS[et];
        po[base + e] = stO[et];
      }
    }

    item = nextItem;
    p ^= 1;
  }
}

// ---------------- combine over chunks (parallelized: 8 e-slabs x 4 c-groups) ----------------
__global__ __launch_bounds__(256) void attn_combine(
    const float* __restrict__ pm, const float* __restrict__ ps,
    const float* __restrict__ po, const int* __restrict__ lens,
    float* __restrict__ out, int C, int Lc)
{
  const int b  = blockIdx.y;
  const int e  = blockIdx.x * 64 + (threadIdx.x & 63);
  const int g  = threadIdx.x >> 6;  // c-group 0..3
  const int n  = lens[b];
  const int cmax = min(C, (n + Lc - 1) / Lc);

  float M = -1e30f, S = 0.f, O = 0.f;
  for (int c = g; c < cmax; c += 4) {
    const size_t base = ((size_t)b * C + c) * EE;
    const float m = pm[base + e];
    const float s = ps[base + e];
    const float o = po[base + e];
    const float Mn  = fmaxf(M, m);
    const float sc0 = __expf(M - Mn);
    const float sc1 = __expf(m - Mn);
    S = S * sc0 + s * sc1;
    O = O * sc0 + o * sc1;
    M = Mn;
  }

  __shared__ float sM[4][64], sS[4][64], sO[4][64];
  sM[g][threadIdx.x & 63] = M;
  sS[g][threadIdx.x & 63] = S;
  sO[g][threadIdx.x & 63] = O;
  __syncthreads();

  if (g == 0) {
    const int le = threadIdx.x & 63;
    float Mt = sM[0][le], St = sS[0][le], Ot = sO[0][le];
#pragma unroll
    for (int gg = 1; gg < 4; gg++) {
      const float m = sM[gg][le];
      const float Mn  = fmaxf(Mt, m);
      const float sc0 = __expf(Mt - Mn);
      const float sc1 = __expf(m - Mn);
      St = St * sc0 + sS[gg][le] * sc1;
      Ot = Ot * sc0 + sO[gg][le] * sc1;
      Mt = Mn;
    }
    out[(size_t)b * EE + e] = Ot / St;  // St > 0: c=0 always valid (lengths >= 1)
  }
}

extern "C" void kernel_launch(void* const* d_in, const int* in_sizes, int n_in,
                              void* d_out, int out_size, void* d_ws, size_t ws_size,
                              hipStream_t stream) {
  const float* enc  = (const float*)d_in[0];
  const int*   lens = (const int*)d_in[1];
  const float* Wh   = (const float*)d_in[2];
  const float* bh   = (const float*)d_in[3];
  const float* Wc   = (const float*)d_in[4];
  float* out = (float*)d_out;

  const size_t wbytes = (size_t)512 * 512 * sizeof(unsigned short);
  int C = 64;  // Lc=32 -> one 32-row pass per item
  while (C > 8 && ws_size < (size_t)3 * BB * C * EE * sizeof(float) + 2 * wbytes + 64)
    C >>= 1;
  const int Lc = LL / C;

  float* pm = (float*)d_ws;
  float* ps = pm + (size_t)BB * C * EE;
  float* po = ps + (size_t)BB * C * EE;
  unsigned short* WhT = (unsigned short*)(po + (size_t)BB * C * EE);
  unsigned short* WcT = WhT + (size_t)512 * 512;
  int* q = (int*)(WcT + (size_t)512 * 512);

  prep_w<<<dim3(64, 2), 256, 0, stream>>>(Wh, Wc, WhT, WcT, q);
  attn_main<<<dim3(256), 512, 0, stream>>>(enc, lens, WhT, bh, WcT, pm, ps, po, q, C, Lc);
  attn_combine<<<dim3(8, BB), 256, 0, stream>>>(pm, ps, po, lens, out, C, Lc);
}